// Round 2
// baseline (748.167 us; speedup 1.0000x reference)
//
#include <hip/hip_runtime.h>
#include <stdint.h>

#define EPS 1e-3f

typedef _Float16 f16x8 __attribute__((ext_vector_type(8)));
typedef float f32x4 __attribute__((ext_vector_type(4)));
typedef float f32x16 __attribute__((ext_vector_type(16)));

// ---------------------------------------------------------------------------
// Setup: fold BN into scale/bias; prepack w_pos into 32x32x16-MFMA A-frags,
// u-packed contraction:  k = kap*8+j = (u = k>>2, y4 = k&3)
//   m = ol*16+kk, frag f = (w*23 + ss)*8 + rel  (rel = y-quad offset)
//   value = w_pos[kk][u][dy = 4*rel + y4 - 2w - ol][ss]  (0 if dy outside [0,23))
// ---------------------------------------------------------------------------
__global__ __launch_bounds__(256) void setup_kernel(
    const float* __restrict__ w_pos,
    const float* __restrict__ gq, const float* __restrict__ bq,
    const float* __restrict__ mq, const float* __restrict__ vq,
    const float* __restrict__ gv, const float* __restrict__ bv,
    const float* __restrict__ mv, const float* __restrict__ vvar,
    float* __restrict__ scale_bias, _Float16* __restrict__ Apack) {
  const int idx = blockIdx.x * 256 + threadIdx.x;
  if (idx < 384) {
    float sc, bi;
    if (idx < 64) {
      const float inv = gq[idx] * rsqrtf(vq[idx] + EPS);
      sc = inv; bi = bq[idx] - mq[idx] * inv;
    } else if (idx < 128) {
      sc = 1.f; bi = 0.f;  // k has no BN
    } else {
      const int o = idx - 128;
      const float inv = gv[o] * rsqrtf(vvar[o] + EPS);
      sc = inv; bi = bv[o] - mv[o] * inv;
    }
    scale_bias[idx] = sc;
    scale_bias[384 + idx] = bi;
  }
  if (idx < 376832) {  // 736 frags * 64 lanes * 8 halfs
    const int j = idx & 7;
    const int lane = (idx >> 3) & 63;
    const int f = idx >> 9;
    const int rel = f & 7;
    const int ss = (f >> 3) % 23;
    const int w = (f >> 3) / 23;
    const int m = lane & 31;
    const int kk = m & 15;
    const int ol = m >> 4;
    const int kap = lane >> 5;
    const int k = kap * 8 + j;
    const int u = k >> 2;
    const int y4 = k & 3;
    const int dy = 4 * rel + y4 - 2 * w - ol;
    float val = 0.f;
    if (dy >= 0 && dy < 23)
      val = w_pos[kk * 2116 + u * 529 + dy * 23 + ss];
    Apack[idx] = (_Float16)val;
  }
}

// ---------------------------------------------------------------------------
// Projection GEMM (unchanged)
// ---------------------------------------------------------------------------
__global__ __launch_bounds__(256) void proj_gemm(
    const float* __restrict__ x,
    const float* __restrict__ w_q, const float* __restrict__ w_k,
    const float* __restrict__ w_v,
    const float* __restrict__ scale_bias,
    float* __restrict__ proj) {
  const int b = blockIdx.z;
  const int ot = blockIdx.y;
  const int nBase = blockIdx.x * 64;
  const int tid = threadIdx.x;
  const int tx = tid & 15, ty = tid >> 4;

  const float* W;
  int oRow;
  if (ot == 0)      { W = w_q; oRow = 0; }
  else if (ot == 1) { W = w_k; oRow = 0; }
  else              { W = w_v; oRow = (ot - 2) * 64; }

  __shared__ float la[32][64];
  __shared__ float lb[32][64];

  float acc[4][4];
#pragma unroll
  for (int i = 0; i < 4; i++)
#pragma unroll
    for (int j = 0; j < 4; j++) acc[i][j] = 0.f;

  const int o_l = tid & 63;
  const int c4a = (tid >> 6) * 4;
  const int cb = tid >> 4;
  const int n4 = (tid & 15) * 4;

  for (int k0 = 0; k0 < 256; k0 += 32) {
    __syncthreads();
#pragma unroll
    for (int rr = 0; rr < 2; rr++) {
      const int c0 = c4a + rr * 16;
      const float4 wv4 = *(const float4*)&W[(size_t)(oRow + o_l) * 256 + k0 + c0];
      la[c0 + 0][o_l] = wv4.x;
      la[c0 + 1][o_l] = wv4.y;
      la[c0 + 2][o_l] = wv4.z;
      la[c0 + 3][o_l] = wv4.w;
    }
#pragma unroll
    for (int rr = 0; rr < 2; rr++) {
      const int c_l = cb + rr * 16;
      const float4 xv =
          *(const float4*)&x[((size_t)(b * 256 + k0 + c_l)) * 4096 + nBase + n4];
      *(float4*)&lb[c_l][n4] = xv;
    }
    __syncthreads();
#pragma unroll
    for (int kk = 0; kk < 32; kk++) {
      const float4 av = *(const float4*)&la[kk][ty * 4];
      const float4 bv = *(const float4*)&lb[kk][tx * 4];
      const float a[4] = {av.x, av.y, av.z, av.w};
      const float bb[4] = {bv.x, bv.y, bv.z, bv.w};
#pragma unroll
      for (int i = 0; i < 4; i++)
#pragma unroll
        for (int j = 0; j < 4; j++) acc[i][j] = fmaf(a[i], bb[j], acc[i][j]);
    }
  }

#pragma unroll
  for (int i = 0; i < 4; i++) {
    const int oG = ot * 64 + ty * 4 + i;
    const float sc = scale_bias[oG];
    const float bi = scale_bias[384 + oG];
    float4 r;
    r.x = fmaf(acc[i][0], sc, bi);
    r.y = fmaf(acc[i][1], sc, bi);
    r.z = fmaf(acc[i][2], sc, bi);
    r.w = fmaf(acc[i][3], sc, bi);
    *(float4*)&proj[((size_t)(b * 384 + oG)) * 4096 + nBase + tx * 4] = r;
  }
}

// ---------------------------------------------------------------------------
// Softmax (unchanged)
// ---------------------------------------------------------------------------
__global__ __launch_bounds__(256) void softmax_k(float* __restrict__ proj) {
  const int row = blockIdx.x;
  const int b = row >> 6, c = row & 63;
  float* p = proj + ((size_t)(b * 384 + 64 + c)) * 4096;
  const int tid = threadIdx.x;

  float4 v[4];
  float vmax = -3.4e38f;
#pragma unroll
  for (int i = 0; i < 4; i++) {
    v[i] = ((const float4*)p)[tid + i * 256];
    vmax = fmaxf(vmax, fmaxf(fmaxf(v[i].x, v[i].y), fmaxf(v[i].z, v[i].w)));
  }
#pragma unroll
  for (int off = 32; off > 0; off >>= 1) vmax = fmaxf(vmax, __shfl_xor(vmax, off));
  __shared__ float redm[4], reds[4];
  if ((tid & 63) == 0) redm[tid >> 6] = vmax;
  __syncthreads();
  vmax = fmaxf(fmaxf(redm[0], redm[1]), fmaxf(redm[2], redm[3]));

  float sum = 0.f;
#pragma unroll
  for (int i = 0; i < 4; i++) {
    v[i].x = expf(v[i].x - vmax); sum += v[i].x;
    v[i].y = expf(v[i].y - vmax); sum += v[i].y;
    v[i].z = expf(v[i].z - vmax); sum += v[i].z;
    v[i].w = expf(v[i].w - vmax); sum += v[i].w;
  }
#pragma unroll
  for (int off = 32; off > 0; off >>= 1) sum += __shfl_xor(sum, off);
  if ((tid & 63) == 0) reds[tid >> 6] = sum;
  __syncthreads();
  sum = reds[0] + reds[1] + reds[2] + reds[3];
  const float inv = 1.f / sum;
#pragma unroll
  for (int i = 0; i < 4; i++) {
    v[i].x *= inv; v[i].y *= inv; v[i].z *= inv; v[i].w *= inv;
    ((float4*)p)[tid + i * 256] = v[i];
  }
}

// ---------------------------------------------------------------------------
// Lc (unchanged)
// ---------------------------------------------------------------------------
__global__ __launch_bounds__(256) void lc_kernel(const float* __restrict__ proj,
                                                 float* __restrict__ Lc) {
  const int kk = blockIdx.x, b = blockIdx.y;
  const int tid = threadIdx.x;
  const int wave = tid >> 6, lane = tid & 63;
  float acc[16];
#pragma unroll
  for (int j = 0; j < 16; j++) acc[j] = 0.f;

  for (int u = 0; u < 4; u++) {
    const float* ks = proj + ((size_t)(b * 384 + 64 + u * 16 + kk)) * 4096;
    const float* vp = proj + ((size_t)(b * 384 + 128 + u * 64 + wave * 16)) * 4096;
    for (int m = lane; m < 4096; m += 64) {
      const float kvl = ks[m];
#pragma unroll
      for (int j = 0; j < 16; j++)
        acc[j] = fmaf(kvl, vp[(size_t)j * 4096 + m], acc[j]);
    }
  }
#pragma unroll
  for (int j = 0; j < 16; j++) {
#pragma unroll
    for (int off = 32; off > 0; off >>= 1) acc[j] += __shfl_xor(acc[j], off);
  }
  if (lane == 0) {
#pragma unroll
    for (int j = 0; j < 16; j++)
      Lc[(b * 16 + kk) * 64 + wave * 16 + j] = acc[j];
  }
}

// ---------------------------------------------------------------------------
// Templated conv worker: all pruning guards compile-time (W = wave index).
// Per ss: branchless straight-line {1 ds_read_b128 prefetch (+4 ahead),
// setprio(1), <=4 MFMA acc[t] += A[rel=tau-2t]*B[tau], setprio(0),
// A-prefetch for ss+1 into dead A[rel] at tau = 14+rel}.
// Zero-frag pruning (compile-time): rel0 dead for W>=2, rel6 for W==0,
// rel7 for W!=3  (-18.75% MFMA).
// ---------------------------------------------------------------------------
template <int W>
__device__ __forceinline__ void conv_worker(
    const _Float16* __restrict__ vL, const f16x8* __restrict__ Awl,
    const float* __restrict__ qsec, const float* __restrict__ lcb,
    const int n, const int kap, const int b, const int dv,
    float* __restrict__ out) {
  constexpr bool G0 = (W < 2);   // rel0 / tau0 live
  constexpr bool G6 = (W != 0);  // rel6 / tau20 live
  constexpr bool G7 = (W == 3);  // rel7 / tau21 live

  f16x8 A[8];
  if (G0) A[0] = Awl[0 * 64];
#pragma unroll
  for (int r = 1; r < 6; ++r) A[r] = Awl[r * 64];
  if (G6) A[6] = Awl[6 * 64];
  if (G7) A[7] = Awl[7 * 64];

#pragma unroll 1
  for (int pass = 0; pass < 2; ++pass) {
    f32x16 acc[8];
#pragma unroll
    for (int t = 0; t < 8; t++) acc[t] = (f32x16)0.f;

#pragma unroll 1
    for (int ss = 0; ss < 23; ++ss) {
      const int ssn = (ss == 22) ? 0 : ss + 1;  // pass-independent A stream
      const f16x8* Awn = Awl + (size_t)(ssn * 8) * 64;
      const _Float16* brow = &vL[(32 * pass + n + ss) * 360 + 8 * kap];

      f16x8 Bq[22];
      // prologue: taus 0..3
      if (G0) Bq[0] = *(const f16x8*)__builtin_assume_aligned(brow, 16);
#pragma unroll
      for (int tau = 1; tau < 4; ++tau)
        Bq[tau] = *(const f16x8*)__builtin_assume_aligned(brow + 16 * tau, 16);

#pragma unroll
      for (int tau = 0; tau < 22; ++tau) {
        // streaming prefetch, 4 taus ahead (compile-time folded guards)
        const int tpf = tau + 4;
        if (tpf < 22) {
          const bool live = (tpf == 20) ? G6 : (tpf == 21) ? G7 : true;
          if (live)
            Bq[tpf] = *(const f16x8*)__builtin_assume_aligned(brow + 16 * tpf, 16);
        }
        __builtin_amdgcn_s_setprio(1);
#pragma unroll
        for (int t = 0; t < 8; ++t) {
          const int rel = tau - 2 * t;
          if (rel < 0 || rel > 7) continue;
          if ((rel == 0 && !G0) || (rel == 6 && !G6) || (rel == 7 && !G7)) continue;
          acc[t] = __builtin_amdgcn_mfma_f32_32x32x16_f16(A[rel], Bq[tau], acc[t], 0, 0, 0);
        }
        __builtin_amdgcn_s_setprio(0);
        // A prefetch for next ss into dead A[rel] (last use at tau = 14+rel)
        if (tau >= 14) {
          const int rn = tau - 14;
          const bool live = (rn == 0) ? G0 : (rn == 6) ? G6 : (rn == 7) ? G7 : true;
          if (live) A[rn] = Awn[rn * 64];
        }
      }
    }

    // epilogue: for each (t, ol): gamma = 8t + 2W + ol
    const int c = 32 * pass + n;
#pragma unroll 1
    for (int t = 0; t < 8; ++t) {
#pragma unroll
      for (int ol = 0; ol < 2; ++ol) {
        const int gamma = 8 * t + 2 * W + ol;
        const float* qg = qsec + (size_t)gamma * 64 + c;
        float y0 = 0.f, y1 = 0.f, y2 = 0.f, y3 = 0.f;
#pragma unroll
        for (int e = 0; e < 8; ++e) {
          const int kk = (e & 3) + 8 * (e >> 2) + 4 * kap;
          const float cf = acc[t][ol * 8 + e] + lcb[e];
          y0 = fmaf(qg[(size_t)(kk) * 4096], cf, y0);
          y1 = fmaf(qg[(size_t)(16 + kk) * 4096], cf, y1);
          y2 = fmaf(qg[(size_t)(32 + kk) * 4096], cf, y2);
          y3 = fmaf(qg[(size_t)(48 + kk) * 4096], cf, y3);
        }
        y0 += __shfl_xor(y0, 32);
        y1 += __shfl_xor(y1, 32);
        y2 += __shfl_xor(y2, 32);
        y3 += __shfl_xor(y3, 32);
        const float s0 = kap ? y2 : y0;  // h = 2*kap
        const float s1 = kap ? y3 : y1;  // h = 2*kap + 1
        out[((size_t)(b * 256 + (2 * kap + 0) * 64 + dv)) * 4096 + gamma * 64 + c] = s0;
        out[((size_t)(b * 256 + (2 * kap + 1) * 64 + dv)) * 4096 + gamma * 64 + c] = s1;
      }
    }
  }
}

// ---------------------------------------------------------------------------
// MFMA position-conv + Yp + Yc. Block = (dv, b). 32x32x16_f16, u-packed K:
//   m = ol*16+kk, n = 32 output cols, k = (u = k>>2, y4 = k&3).
// LDS: vL[x'][tau][u][y4], row = 22 quads * 16 + 8 pad = 360 halfs (720 B).
// Worker is template-specialized on wave index (compile-time pruning,
// branchless inner loop) and dispatched via uniform switch.
// ---------------------------------------------------------------------------
__global__ __launch_bounds__(256, 2) void lambda_conv(
    const float* __restrict__ proj, const _Float16* __restrict__ Apack,
    const float* __restrict__ Lc, const float* __restrict__ b_pos,
    float* __restrict__ out) {
  const int dv = blockIdx.x;
  const int b = blockIdx.y;
  const int tid = threadIdx.x;
  const int w = tid >> 6;          // wave: off pair base {2w, 2w+1}
  const int lane = tid & 63;
  const int n = lane & 31;         // output col within pass
  const int kap = lane >> 5;

  __shared__ __align__(16) _Float16 vL[86 * 360];  // 61920 B

  // zero LDS (halo + pad)
  {
    const uint4 z = {0u, 0u, 0u, 0u};
    for (int i = tid; i < (86 * 360 * 2) / 16; i += 256) ((uint4*)vL)[i] = z;
  }
  __syncthreads();

  // stage v (f32 -> f16), transposed + u-packed: vL[x+11][sy>>2][u][sy&3]
  {
    const float* vsec = proj + ((size_t)(b * 384 + 128 + dv)) * 4096;
    for (int idx = tid; idx < 4096; idx += 256) {
      const int u = idx >> 10, g = (idx >> 4) & 63, c4 = (idx & 15) * 4;
      const float4 vv = *(const float4*)&vsec[(size_t)u * 64 * 4096 + g * 64 + c4];
      const int sy = g + 11;
      const int qoff = (sy >> 2) * 16 + (u << 2) + (sy & 3);
      _Float16* base = &vL[(c4 + 11) * 360 + qoff];
      base[0 * 360] = (_Float16)vv.x;
      base[1 * 360] = (_Float16)vv.y;
      base[2 * 360] = (_Float16)vv.z;
      base[3 * 360] = (_Float16)vv.w;
    }
  }
  __syncthreads();

  // Lc + b_pos for this lane's 8 kk channels: kk_e = (e&3) + 8*(e>>2) + 4*kap
  float lcb[8];
#pragma unroll
  for (int e = 0; e < 8; e++) {
    const int kk = (e & 3) + 8 * (e >> 2) + 4 * kap;
    lcb[e] = Lc[(b * 16 + kk) * 64 + dv] + b_pos[kk];
  }

  const float* qsec = proj + ((size_t)(b * 384)) * 4096;
  const f16x8* Ap = (const f16x8*)Apack;
  const f16x8* Awl = Ap + (size_t)(w * 184) * 64 + lane;  // frag (ss*8+rel)*64

  switch (w) {
    case 0: conv_worker<0>(vL, Awl, qsec, lcb, n, kap, b, dv, out); break;
    case 1: conv_worker<1>(vL, Awl, qsec, lcb, n, kap, b, dv, out); break;
    case 2: conv_worker<2>(vL, Awl, qsec, lcb, n, kap, b, dv, out); break;
    default: conv_worker<3>(vL, Awl, qsec, lcb, n, kap, b, dv, out); break;
  }
}

// ---------------------------------------------------------------------------
extern "C" void kernel_launch(void* const* d_in, const int* in_sizes, int n_in,
                              void* d_out, int out_size, void* d_ws, size_t ws_size,
                              hipStream_t stream) {
  const float* x       = (const float*)d_in[0];
  const float* w_q     = (const float*)d_in[1];
  const float* w_k     = (const float*)d_in[2];
  const float* w_v     = (const float*)d_in[3];
  const float* gamma_q = (const float*)d_in[4];
  const float* beta_q  = (const float*)d_in[5];
  const float* mean_q  = (const float*)d_in[6];
  const float* var_q   = (const float*)d_in[7];
  const float* gamma_v = (const float*)d_in[8];
  const float* beta_v  = (const float*)d_in[9];
  const float* mean_v  = (const float*)d_in[10];
  const float* var_v   = (const float*)d_in[11];
  const float* w_pos   = (const float*)d_in[12];
  const float* b_pos   = (const float*)d_in[13];

  float* ws = (float*)d_ws;
  float* proj = ws;                            // 16*384*4096 floats
  float* sb   = ws + 25165824;                 // 768 floats
  float* Lc   = sb + 768;                      // 16384 floats
  _Float16* Apack = (_Float16*)(Lc + 16384);   // 376832 halfs
  float* out = (float*)d_out;

  setup_kernel<<<1472, 256, 0, stream>>>(w_pos, gamma_q, beta_q, mean_q, var_q,
                                         gamma_v, beta_v, mean_v, var_v, sb, Apack);
  proj_gemm<<<dim3(64, 6, 16), 256, 0, stream>>>(x, w_q, w_k, w_v, sb, proj);
  softmax_k<<<1024, 256, 0, stream>>>(proj);
  lc_kernel<<<dim3(16, 16), 256, 0, stream>>>(proj, Lc);
  lambda_conv<<<dim3(64, 16), 256, 0, stream>>>(proj, Apack, Lc, b_pos, out);
}

// Round 3
// 619.563 us; speedup vs baseline: 1.2076x; 1.2076x over previous
//
#include <hip/hip_runtime.h>
#include <stdint.h>

#define EPS 1e-3f

typedef _Float16 f16x8 __attribute__((ext_vector_type(8)));
typedef float f32x4 __attribute__((ext_vector_type(4)));
typedef float f32x16 __attribute__((ext_vector_type(16)));

// ---------------------------------------------------------------------------
// Setup: fold BN into scale/bias; zero Lc (lc_kernel accumulates atomically);
// pack Wt[k][row] = W_row[k] * scale(row) (384 rows = q|k|v sections);
// prepack w_pos into 32x32x16-MFMA A-frags, u-packed contraction:
//   k = kap*8+j = (u = k>>2, y4 = k&3), m = ol*16+kk,
//   frag f = (w*23 + ss)*8 + rel, value = w_pos[kk][u][4rel+y4-2w-ol][ss]
// ---------------------------------------------------------------------------
__global__ __launch_bounds__(256) void setup_kernel(
    const float* __restrict__ w_pos,
    const float* __restrict__ w_q, const float* __restrict__ w_k,
    const float* __restrict__ w_v,
    const float* __restrict__ gq, const float* __restrict__ bq,
    const float* __restrict__ mq, const float* __restrict__ vq,
    const float* __restrict__ gv, const float* __restrict__ bv,
    const float* __restrict__ mv, const float* __restrict__ vvar,
    float* __restrict__ scale_bias, float* __restrict__ Lc,
    float* __restrict__ Wt, _Float16* __restrict__ Apack) {
  const int idx = blockIdx.x * 256 + threadIdx.x;
  if (idx < 384) {
    float sc, bi;
    if (idx < 64) {
      const float inv = gq[idx] * rsqrtf(vq[idx] + EPS);
      sc = inv; bi = bq[idx] - mq[idx] * inv;
    } else if (idx < 128) {
      sc = 1.f; bi = 0.f;  // k has no BN
    } else {
      const int o = idx - 128;
      const float inv = gv[o] * rsqrtf(vvar[o] + EPS);
      sc = inv; bi = bv[o] - mv[o] * inv;
    }
    scale_bias[idx] = sc;
    scale_bias[384 + idx] = bi;
  }
  if (idx < 16384) Lc[idx] = 0.f;  // lc_kernel accumulates via atomicAdd
  if (idx < 98304) {               // Wt[k*384 + row], row fastest (coalesced wr)
    const int row = idx % 384;
    const int k = idx / 384;
    float sc; const float* Wsrc;
    if (row < 64) {
      sc = gq[row] * rsqrtf(vq[row] + EPS);
      Wsrc = w_q + (size_t)row * 256;
    } else if (row < 128) {
      sc = 1.f;
      Wsrc = w_k + (size_t)(row - 64) * 256;
    } else {
      const int r = row - 128;
      sc = gv[r] * rsqrtf(vvar[r] + EPS);
      Wsrc = w_v + (size_t)r * 256;
    }
    Wt[idx] = Wsrc[k] * sc;
  }
  if (idx < 376832) {  // 736 frags * 64 lanes * 8 halfs
    const int j = idx & 7;
    const int lane = (idx >> 3) & 63;
    const int f = idx >> 9;
    const int rel = f & 7;
    const int ss = (f >> 3) % 23;
    const int w = (f >> 3) / 23;
    const int m = lane & 31;
    const int kk = m & 15;
    const int ol = m >> 4;
    const int kap = lane >> 5;
    const int k = kap * 8 + j;
    const int u = k >> 2;
    const int y4 = k & 3;
    const int dy = 4 * rel + y4 - 2 * w - ol;
    float val = 0.f;
    if (dy >= 0 && dy < 23)
      val = w_pos[kk * 2116 + u * 529 + dy * 23 + ss];
    Apack[idx] = (_Float16)val;
  }
}

// ---------------------------------------------------------------------------
// Projection GEMM, all 384 output rows per block (x read ONCE).
// Block (nchunk, b): 64 cols x 384 rows. Thread: acc[6 sections][4 rows][4 cols].
// Wt is pre-transposed + BN-scale-folded -> staging is a linear float4 copy.
// ---------------------------------------------------------------------------
__global__ __launch_bounds__(256, 2) void proj_gemm(
    const float* __restrict__ x, const float* __restrict__ Wt,
    const float* __restrict__ scale_bias, float* __restrict__ proj) {
  const int b = blockIdx.y;
  const int nBase = blockIdx.x * 64;
  const int tid = threadIdx.x;
  const int tx = tid & 15, ty = tid >> 4;

  __shared__ float la[32][384];  // [k][row]  48 KB
  __shared__ float lb[32][64];   // [k][n]     8 KB

  float acc[6][4][4];
#pragma unroll
  for (int s = 0; s < 6; s++)
#pragma unroll
    for (int i = 0; i < 4; i++)
#pragma unroll
      for (int j = 0; j < 4; j++) acc[s][i][j] = 0.f;

  for (int k0 = 0; k0 < 256; k0 += 32) {
    __syncthreads();
    // stage Wt rows k0..k0+31 (each 384 floats): linear copy, 12 float4/thread
    {
      const float4* src = (const float4*)&Wt[(size_t)k0 * 384];
      float4* dst = (float4*)&la[0][0];
#pragma unroll
      for (int r = 0; r < 12; ++r) dst[tid + r * 256] = src[tid + r * 256];
    }
    // stage x tile 32 k x 64 n: 2 float4/thread
#pragma unroll
    for (int r = 0; r < 2; ++r) {
      const int i = tid + r * 256;
      const int c = i >> 4, n4 = (i & 15) * 4;
      *(float4*)&lb[c][n4] =
          *(const float4*)&x[((size_t)(b * 256 + k0 + c)) * 4096 + nBase + n4];
    }
    __syncthreads();
    for (int kk = 0; kk < 32; ++kk) {
      const float4 bv = *(const float4*)&lb[kk][tx * 4];
      const float bb[4] = {bv.x, bv.y, bv.z, bv.w};
#pragma unroll
      for (int s = 0; s < 6; ++s) {
        const float4 av = *(const float4*)&la[kk][s * 64 + ty * 4];
        const float a[4] = {av.x, av.y, av.z, av.w};
#pragma unroll
        for (int i = 0; i < 4; i++)
#pragma unroll
          for (int j = 0; j < 4; j++)
            acc[s][i][j] = fmaf(a[i], bb[j], acc[s][i][j]);
      }
    }
  }

#pragma unroll
  for (int s = 0; s < 6; ++s) {
#pragma unroll
    for (int i = 0; i < 4; i++) {
      const int oG = s * 64 + ty * 4 + i;
      const float bi = scale_bias[384 + oG];  // scale already folded into Wt
      float4 r;
      r.x = acc[s][i][0] + bi;
      r.y = acc[s][i][1] + bi;
      r.z = acc[s][i][2] + bi;
      r.w = acc[s][i][3] + bi;
      *(float4*)&proj[((size_t)(b * 384 + oG)) * 4096 + nBase + tx * 4] = r;
    }
  }
}

// ---------------------------------------------------------------------------
// Softmax (unchanged)
// ---------------------------------------------------------------------------
__global__ __launch_bounds__(256) void softmax_k(float* __restrict__ proj) {
  const int row = blockIdx.x;
  const int b = row >> 6, c = row & 63;
  float* p = proj + ((size_t)(b * 384 + 64 + c)) * 4096;
  const int tid = threadIdx.x;

  float4 v[4];
  float vmax = -3.4e38f;
#pragma unroll
  for (int i = 0; i < 4; i++) {
    v[i] = ((const float4*)p)[tid + i * 256];
    vmax = fmaxf(vmax, fmaxf(fmaxf(v[i].x, v[i].y), fmaxf(v[i].z, v[i].w)));
  }
#pragma unroll
  for (int off = 32; off > 0; off >>= 1) vmax = fmaxf(vmax, __shfl_xor(vmax, off));
  __shared__ float redm[4], reds[4];
  if ((tid & 63) == 0) redm[tid >> 6] = vmax;
  __syncthreads();
  vmax = fmaxf(fmaxf(redm[0], redm[1]), fmaxf(redm[2], redm[3]));

  float sum = 0.f;
#pragma unroll
  for (int i = 0; i < 4; i++) {
    v[i].x = expf(v[i].x - vmax); sum += v[i].x;
    v[i].y = expf(v[i].y - vmax); sum += v[i].y;
    v[i].z = expf(v[i].z - vmax); sum += v[i].z;
    v[i].w = expf(v[i].w - vmax); sum += v[i].w;
  }
#pragma unroll
  for (int off = 32; off > 0; off >>= 1) sum += __shfl_xor(sum, off);
  if ((tid & 63) == 0) reds[tid >> 6] = sum;
  __syncthreads();
  sum = reds[0] + reds[1] + reds[2] + reds[3];
  const float inv = 1.f / sum;
#pragma unroll
  for (int i = 0; i < 4; i++) {
    v[i].x *= inv; v[i].y *= inv; v[i].z *= inv; v[i].w *= inv;
    ((float4*)p)[tid + i * 256] = v[i];
  }
}

// ---------------------------------------------------------------------------
// Lc: grid (mchunk=32, b=16). Each block stages k (16x128) and v (64x128)
// tiles per u in LDS, serial-m per thread (no cross-lane reduce), atomicAdd
// partial [16 kk][64 dv] into Lc (zeroed by setup). v read ONCE per m-chunk.
// ---------------------------------------------------------------------------
__global__ __launch_bounds__(256) void lc_kernel(const float* __restrict__ proj,
                                                 float* __restrict__ Lc) {
  const int mc = blockIdx.x, b = blockIdx.y;
  const int m0 = mc * 128;
  const int tid = threadIdx.x;
  const int kk = tid & 15;
  const int dvb = tid >> 4;  // 16 groups of 4 dv

  __shared__ float kT[16][132];
  __shared__ float vT[64][132];

  float a0 = 0.f, a1 = 0.f, a2 = 0.f, a3 = 0.f;

  for (int u = 0; u < 4; ++u) {
    __syncthreads();
#pragma unroll
    for (int r = 0; r < 2; ++r) {  // k: 512 float4
      const int i = tid + r * 256;
      const int row = i >> 5, c4 = (i & 31) * 4;
      *(float4*)&kT[row][c4] =
          *(const float4*)&proj[((size_t)(b * 384 + 64 + u * 16 + row)) * 4096 + m0 + c4];
    }
#pragma unroll
    for (int r = 0; r < 8; ++r) {  // v: 2048 float4
      const int i = tid + r * 256;
      const int row = i >> 5, c4 = (i & 31) * 4;
      *(float4*)&vT[row][c4] =
          *(const float4*)&proj[((size_t)(b * 384 + 128 + u * 64 + row)) * 4096 + m0 + c4];
    }
    __syncthreads();
#pragma unroll 4
    for (int m = 0; m < 128; ++m) {
      const float kv = kT[kk][m];
      a0 = fmaf(kv, vT[dvb * 4 + 0][m], a0);
      a1 = fmaf(kv, vT[dvb * 4 + 1][m], a1);
      a2 = fmaf(kv, vT[dvb * 4 + 2][m], a2);
      a3 = fmaf(kv, vT[dvb * 4 + 3][m], a3);
    }
  }

  float* dst = &Lc[((size_t)(b * 16 + kk)) * 64 + dvb * 4];
  atomicAdd(dst + 0, a0);
  atomicAdd(dst + 1, a1);
  atomicAdd(dst + 2, a2);
  atomicAdd(dst + 3, a3);
}

// ---------------------------------------------------------------------------
// Templated conv worker (unchanged from round 2): compile-time pruning,
// branchless inner loop, setprio around MFMA cluster, A/B streaming prefetch.
// ---------------------------------------------------------------------------
template <int W>
__device__ __forceinline__ void conv_worker(
    const _Float16* __restrict__ vL, const f16x8* __restrict__ Awl,
    const float* __restrict__ qsec, const float* __restrict__ lcb,
    const int n, const int kap, const int b, const int dv,
    float* __restrict__ out) {
  constexpr bool G0 = (W < 2);   // rel0 / tau0 live
  constexpr bool G6 = (W != 0);  // rel6 / tau20 live
  constexpr bool G7 = (W == 3);  // rel7 / tau21 live

  f16x8 A[8];
  if (G0) A[0] = Awl[0 * 64];
#pragma unroll
  for (int r = 1; r < 6; ++r) A[r] = Awl[r * 64];
  if (G6) A[6] = Awl[6 * 64];
  if (G7) A[7] = Awl[7 * 64];

#pragma unroll 1
  for (int pass = 0; pass < 2; ++pass) {
    f32x16 acc[8];
#pragma unroll
    for (int t = 0; t < 8; t++) acc[t] = (f32x16)0.f;

#pragma unroll 1
    for (int ss = 0; ss < 23; ++ss) {
      const int ssn = (ss == 22) ? 0 : ss + 1;  // pass-independent A stream
      const f16x8* Awn = Awl + (size_t)(ssn * 8) * 64;
      const _Float16* brow = &vL[(32 * pass + n + ss) * 360 + 8 * kap];

      f16x8 Bq[22];
      // prologue: taus 0..3
      if (G0) Bq[0] = *(const f16x8*)__builtin_assume_aligned(brow, 16);
#pragma unroll
      for (int tau = 1; tau < 4; ++tau)
        Bq[tau] = *(const f16x8*)__builtin_assume_aligned(brow + 16 * tau, 16);

#pragma unroll
      for (int tau = 0; tau < 22; ++tau) {
        // streaming prefetch, 4 taus ahead (compile-time folded guards)
        const int tpf = tau + 4;
        if (tpf < 22) {
          const bool live = (tpf == 20) ? G6 : (tpf == 21) ? G7 : true;
          if (live)
            Bq[tpf] = *(const f16x8*)__builtin_assume_aligned(brow + 16 * tpf, 16);
        }
        __builtin_amdgcn_s_setprio(1);
#pragma unroll
        for (int t = 0; t < 8; ++t) {
          const int rel = tau - 2 * t;
          if (rel < 0 || rel > 7) continue;
          if ((rel == 0 && !G0) || (rel == 6 && !G6) || (rel == 7 && !G7)) continue;
          acc[t] = __builtin_amdgcn_mfma_f32_32x32x16_f16(A[rel], Bq[tau], acc[t], 0, 0, 0);
        }
        __builtin_amdgcn_s_setprio(0);
        // A prefetch for next ss into dead A[rel] (last use at tau = 14+rel)
        if (tau >= 14) {
          const int rn = tau - 14;
          const bool live = (rn == 0) ? G0 : (rn == 6) ? G6 : (rn == 7) ? G7 : true;
          if (live) A[rn] = Awn[rn * 64];
        }
      }
    }

    // epilogue: for each (t, ol): gamma = 8t + 2W + ol
    const int c = 32 * pass + n;
#pragma unroll 1
    for (int t = 0; t < 8; ++t) {
#pragma unroll
      for (int ol = 0; ol < 2; ++ol) {
        const int gamma = 8 * t + 2 * W + ol;
        const float* qg = qsec + (size_t)gamma * 64 + c;
        float y0 = 0.f, y1 = 0.f, y2 = 0.f, y3 = 0.f;
#pragma unroll
        for (int e = 0; e < 8; ++e) {
          const int kk = (e & 3) + 8 * (e >> 2) + 4 * kap;
          const float cf = acc[t][ol * 8 + e] + lcb[e];
          y0 = fmaf(qg[(size_t)(kk) * 4096], cf, y0);
          y1 = fmaf(qg[(size_t)(16 + kk) * 4096], cf, y1);
          y2 = fmaf(qg[(size_t)(32 + kk) * 4096], cf, y2);
          y3 = fmaf(qg[(size_t)(48 + kk) * 4096], cf, y3);
        }
        y0 += __shfl_xor(y0, 32);
        y1 += __shfl_xor(y1, 32);
        y2 += __shfl_xor(y2, 32);
        y3 += __shfl_xor(y3, 32);
        const float s0 = kap ? y2 : y0;  // h = 2*kap
        const float s1 = kap ? y3 : y1;  // h = 2*kap + 1
        out[((size_t)(b * 256 + (2 * kap + 0) * 64 + dv)) * 4096 + gamma * 64 + c] = s0;
        out[((size_t)(b * 256 + (2 * kap + 1) * 64 + dv)) * 4096 + gamma * 64 + c] = s1;
      }
    }
  }
}

// ---------------------------------------------------------------------------
// MFMA position-conv + Yp + Yc (unchanged).
// ---------------------------------------------------------------------------
__global__ __launch_bounds__(256, 2) void lambda_conv(
    const float* __restrict__ proj, const _Float16* __restrict__ Apack,
    const float* __restrict__ Lc, const float* __restrict__ b_pos,
    float* __restrict__ out) {
  const int dv = blockIdx.x;
  const int b = blockIdx.y;
  const int tid = threadIdx.x;
  const int w = tid >> 6;          // wave: off pair base {2w, 2w+1}
  const int lane = tid & 63;
  const int n = lane & 31;         // output col within pass
  const int kap = lane >> 5;

  __shared__ __align__(16) _Float16 vL[86 * 360];  // 61920 B

  // zero LDS (halo + pad)
  {
    const uint4 z = {0u, 0u, 0u, 0u};
    for (int i = tid; i < (86 * 360 * 2) / 16; i += 256) ((uint4*)vL)[i] = z;
  }
  __syncthreads();

  // stage v (f32 -> f16), transposed + u-packed: vL[x+11][sy>>2][u][sy&3]
  {
    const float* vsec = proj + ((size_t)(b * 384 + 128 + dv)) * 4096;
    for (int idx = tid; idx < 4096; idx += 256) {
      const int u = idx >> 10, g = (idx >> 4) & 63, c4 = (idx & 15) * 4;
      const float4 vv = *(const float4*)&vsec[(size_t)u * 64 * 4096 + g * 64 + c4];
      const int sy = g + 11;
      const int qoff = (sy >> 2) * 16 + (u << 2) + (sy & 3);
      _Float16* base = &vL[(c4 + 11) * 360 + qoff];
      base[0 * 360] = (_Float16)vv.x;
      base[1 * 360] = (_Float16)vv.y;
      base[2 * 360] = (_Float16)vv.z;
      base[3 * 360] = (_Float16)vv.w;
    }
  }
  __syncthreads();

  // Lc + b_pos for this lane's 8 kk channels: kk_e = (e&3) + 8*(e>>2) + 4*kap
  float lcb[8];
#pragma unroll
  for (int e = 0; e < 8; e++) {
    const int kk = (e & 3) + 8 * (e >> 2) + 4 * kap;
    lcb[e] = Lc[(b * 16 + kk) * 64 + dv] + b_pos[kk];
  }

  const float* qsec = proj + ((size_t)(b * 384)) * 4096;
  const f16x8* Ap = (const f16x8*)Apack;
  const f16x8* Awl = Ap + (size_t)(w * 184) * 64 + lane;  // frag (ss*8+rel)*64

  switch (w) {
    case 0: conv_worker<0>(vL, Awl, qsec, lcb, n, kap, b, dv, out); break;
    case 1: conv_worker<1>(vL, Awl, qsec, lcb, n, kap, b, dv, out); break;
    case 2: conv_worker<2>(vL, Awl, qsec, lcb, n, kap, b, dv, out); break;
    default: conv_worker<3>(vL, Awl, qsec, lcb, n, kap, b, dv, out); break;
  }
}

// ---------------------------------------------------------------------------
extern "C" void kernel_launch(void* const* d_in, const int* in_sizes, int n_in,
                              void* d_out, int out_size, void* d_ws, size_t ws_size,
                              hipStream_t stream) {
  const float* x       = (const float*)d_in[0];
  const float* w_q     = (const float*)d_in[1];
  const float* w_k     = (const float*)d_in[2];
  const float* w_v     = (const float*)d_in[3];
  const float* gamma_q = (const float*)d_in[4];
  const float* beta_q  = (const float*)d_in[5];
  const float* mean_q  = (const float*)d_in[6];
  const float* var_q   = (const float*)d_in[7];
  const float* gamma_v = (const float*)d_in[8];
  const float* beta_v  = (const float*)d_in[9];
  const float* mean_v  = (const float*)d_in[10];
  const float* var_v   = (const float*)d_in[11];
  const float* w_pos   = (const float*)d_in[12];
  const float* b_pos   = (const float*)d_in[13];

  float* ws = (float*)d_ws;
  float* proj = ws;                            // 25165824 floats
  float* sb   = ws + 25165824;                 // 768 floats
  float* Lc   = sb + 768;                      // 16384 floats
  _Float16* Apack = (_Float16*)(Lc + 16384);   // 376832 halfs
  float* Wt   = (float*)(Apack + 376832);      // 98304 floats
  float* out = (float*)d_out;

  setup_kernel<<<1472, 256, 0, stream>>>(w_pos, w_q, w_k, w_v,
                                         gamma_q, beta_q, mean_q, var_q,
                                         gamma_v, beta_v, mean_v, var_v,
                                         sb, Lc, Wt, Apack);
  proj_gemm<<<dim3(64, 16), 256, 0, stream>>>(x, Wt, sb, proj);
  softmax_k<<<1024, 256, 0, stream>>>(proj);
  lc_kernel<<<dim3(32, 16), 256, 0, stream>>>(proj, Lc);
  lambda_conv<<<dim3(64, 16), 256, 0, stream>>>(proj, Apack, Lc, b_pos, out);
}

// Round 5
// 559.960 us; speedup vs baseline: 1.3361x; 1.1064x over previous
//
#include <hip/hip_runtime.h>
#include <stdint.h>

#define EPS 1e-3f

typedef _Float16 f16x8 __attribute__((ext_vector_type(8)));
typedef float f32x4 __attribute__((ext_vector_type(4)));
typedef float f32x16 __attribute__((ext_vector_type(16)));

// Compile-time pruning tables for the position-conv MFMA lattice.
// rel = y-quad offset of A-frag; zero-frag when dy range 4rel+[-1,3]-2W misses [0,23).
template <int W>
constexpr bool rel_live(int rel) {
  return !(rel < 0 || rel > 7 || (rel == 0 && W >= 2) ||
           (rel == 6 && W == 0) || (rel == 7 && W != 3));
}
template <int W, int H>
constexpr bool tau_live(int tau) {
  for (int tt = 0; tt < 4; ++tt)
    if (rel_live<W>(tau - 2 * (4 * H + tt))) return true;
  return false;
}

// ---------------------------------------------------------------------------
// Setup: fold BN scale/bias; zero Lc; pack Wp (proj weights as f16 MFMA
// A-frags: m = mt*32+(lane&31), k = kt*16+(lane>>5)*8+j, scale folded);
// prepack w_pos into 32x32x16-MFMA A-frags (u-packed K: u=k>>2, y4=k&3).
// ---------------------------------------------------------------------------
__global__ __launch_bounds__(256) void setup_kernel(
    const float* __restrict__ w_pos,
    const float* __restrict__ w_q, const float* __restrict__ w_k,
    const float* __restrict__ w_v,
    const float* __restrict__ gq, const float* __restrict__ bq,
    const float* __restrict__ mq, const float* __restrict__ vq,
    const float* __restrict__ gv, const float* __restrict__ bv,
    const float* __restrict__ mv, const float* __restrict__ vvar,
    float* __restrict__ scale_bias, float* __restrict__ Lc,
    _Float16* __restrict__ Wp, _Float16* __restrict__ Apack) {
  const int idx = blockIdx.x * 256 + threadIdx.x;
  if (idx < 384) {
    float sc, bi;
    if (idx < 64) {
      const float inv = gq[idx] * rsqrtf(vq[idx] + EPS);
      sc = inv; bi = bq[idx] - mq[idx] * inv;
    } else if (idx < 128) {
      sc = 1.f; bi = 0.f;  // k has no BN
    } else {
      const int o = idx - 128;
      const float inv = gv[o] * rsqrtf(vvar[o] + EPS);
      sc = inv; bi = bv[o] - mv[o] * inv;
    }
    scale_bias[idx] = sc;
    scale_bias[384 + idx] = bi;
  }
  if (idx < 16384) Lc[idx] = 0.f;  // lc_kernel accumulates via atomicAdd
  if (idx < 98304) {               // Wp A-frag pack: idx = ((mt*16+kt)*64+lane)*8+j
    const int j = idx & 7;
    const int lane = (idx >> 3) & 63;
    const int fr = idx >> 9;       // mt*16 + kt
    const int kt = fr & 15;
    const int mt = fr >> 4;
    const int m = mt * 32 + (lane & 31);
    const int k = kt * 16 + (lane >> 5) * 8 + j;
    float sc; const float* Wsrc;
    if (m < 64) {
      sc = gq[m] * rsqrtf(vq[m] + EPS);
      Wsrc = w_q + (size_t)m * 256;
    } else if (m < 128) {
      sc = 1.f;
      Wsrc = w_k + (size_t)(m - 64) * 256;
    } else {
      const int r = m - 128;
      sc = gv[r] * rsqrtf(vvar[r] + EPS);
      Wsrc = w_v + (size_t)r * 256;
    }
    Wp[idx] = (_Float16)(Wsrc[k] * sc);
  }
  if (idx < 376832) {  // 736 frags * 64 lanes * 8 halfs
    const int j = idx & 7;
    const int lane = (idx >> 3) & 63;
    const int f = idx >> 9;
    const int rel = f & 7;
    const int ss = (f >> 3) % 23;
    const int w = (f >> 3) / 23;
    const int m = lane & 31;
    const int kk = m & 15;
    const int ol = m >> 4;
    const int kap = lane >> 5;
    const int k = kap * 8 + j;
    const int u = k >> 2;
    const int y4 = k & 3;
    const int dy = 4 * rel + y4 - 2 * w - ol;
    float val = 0.f;
    if (dy >= 0 && dy < 23)
      val = w_pos[kk * 2116 + u * 529 + dy * 23 + ss];
    Apack[idx] = (_Float16)val;
  }
}

// ---------------------------------------------------------------------------
// Projection GEMM via f16 MFMA. Block (nchunk=128 of 32 cols, b).
// Stage x-tile f16 transposed in LDS (264-half padded rows), then 16 k-steps
// x 3 m-tiles per wave. A-frags stream from L2-resident Wp. Memory-bound.
// ---------------------------------------------------------------------------
__global__ __launch_bounds__(256) void proj_gemm(
    const float* __restrict__ x, const _Float16* __restrict__ Wp,
    const float* __restrict__ scale_bias, float* __restrict__ proj) {
  const int b = blockIdx.y;
  const int n0 = blockIdx.x * 32;
  const int tid = threadIdx.x;
  const int w = tid >> 6, lane = tid & 63;
  const int col = lane & 31, kap = lane >> 5;

  __shared__ __align__(16) _Float16 xT[32][264];  // 16896 B

  // stage x f32 -> f16 transposed: xT[n][k]
#pragma unroll
  for (int r = 0; r < 8; ++r) {
    const int i = tid + r * 256;  // 0..2047
    const int k = i >> 3, n4 = (i & 7) * 4;
    const float4 xv = *(const float4*)&x[((size_t)(b * 256 + k)) * 4096 + n0 + n4];
    xT[n4 + 0][k] = (_Float16)xv.x;
    xT[n4 + 1][k] = (_Float16)xv.y;
    xT[n4 + 2][k] = (_Float16)xv.z;
    xT[n4 + 3][k] = (_Float16)xv.w;
  }
  __syncthreads();

  f32x16 acc[3];
#pragma unroll
  for (int i = 0; i < 3; ++i) acc[i] = (f32x16)0.f;

  const f16x8* Wf = (const f16x8*)Wp;
#pragma unroll
  for (int kt = 0; kt < 16; ++kt) {
    const f16x8 B =
        *(const f16x8*)__builtin_assume_aligned(&xT[col][kt * 16 + kap * 8], 16);
#pragma unroll
    for (int i = 0; i < 3; ++i) {
      const f16x8 A = Wf[(size_t)(((w * 3 + i) * 16 + kt) * 64) + lane];
      acc[i] = __builtin_amdgcn_mfma_f32_32x32x16_f16(A, B, acc[i], 0, 0, 0);
    }
  }

#pragma unroll
  for (int i = 0; i < 3; ++i) {
    const int mt = w * 3 + i;
#pragma unroll
    for (int reg = 0; reg < 16; ++reg) {
      const int row = (reg & 3) + 8 * (reg >> 2) + 4 * kap;
      const int o = mt * 32 + row;
      proj[((size_t)(b * 384 + o)) * 4096 + n0 + col] =
          acc[i][reg] + scale_bias[384 + o];
    }
  }
}

// ---------------------------------------------------------------------------
// Softmax (unchanged)
// ---------------------------------------------------------------------------
__global__ __launch_bounds__(256) void softmax_k(float* __restrict__ proj) {
  const int row = blockIdx.x;
  const int b = row >> 6, c = row & 63;
  float* p = proj + ((size_t)(b * 384 + 64 + c)) * 4096;
  const int tid = threadIdx.x;

  float4 v[4];
  float vmax = -3.4e38f;
#pragma unroll
  for (int i = 0; i < 4; i++) {
    v[i] = ((const float4*)p)[tid + i * 256];
    vmax = fmaxf(vmax, fmaxf(fmaxf(v[i].x, v[i].y), fmaxf(v[i].z, v[i].w)));
  }
#pragma unroll
  for (int off = 32; off > 0; off >>= 1) vmax = fmaxf(vmax, __shfl_xor(vmax, off));
  __shared__ float redm[4], reds[4];
  if ((tid & 63) == 0) redm[tid >> 6] = vmax;
  __syncthreads();
  vmax = fmaxf(fmaxf(redm[0], redm[1]), fmaxf(redm[2], redm[3]));

  float sum = 0.f;
#pragma unroll
  for (int i = 0; i < 4; i++) {
    v[i].x = expf(v[i].x - vmax); sum += v[i].x;
    v[i].y = expf(v[i].y - vmax); sum += v[i].y;
    v[i].z = expf(v[i].z - vmax); sum += v[i].z;
    v[i].w = expf(v[i].w - vmax); sum += v[i].w;
  }
#pragma unroll
  for (int off = 32; off > 0; off >>= 1) sum += __shfl_xor(sum, off);
  if ((tid & 63) == 0) reds[tid >> 6] = sum;
  __syncthreads();
  sum = reds[0] + reds[1] + reds[2] + reds[3];
  const float inv = 1.f / sum;
#pragma unroll
  for (int i = 0; i < 4; i++) {
    v[i].x *= inv; v[i].y *= inv; v[i].z *= inv; v[i].w *= inv;
    ((float4*)p)[tid + i * 256] = v[i];
  }
}

// ---------------------------------------------------------------------------
// Lc (unchanged): LDS-tiled, atomicAdd partials.
// ---------------------------------------------------------------------------
__global__ __launch_bounds__(256) void lc_kernel(const float* __restrict__ proj,
                                                 float* __restrict__ Lc) {
  const int mc = blockIdx.x, b = blockIdx.y;
  const int m0 = mc * 128;
  const int tid = threadIdx.x;
  const int kk = tid & 15;
  const int dvb = tid >> 4;  // 16 groups of 4 dv

  __shared__ float kT[16][132];
  __shared__ float vT[64][132];

  float a0 = 0.f, a1 = 0.f, a2 = 0.f, a3 = 0.f;

  for (int u = 0; u < 4; ++u) {
    __syncthreads();
#pragma unroll
    for (int r = 0; r < 2; ++r) {  // k: 512 float4
      const int i = tid + r * 256;
      const int row = i >> 5, c4 = (i & 31) * 4;
      *(float4*)&kT[row][c4] =
          *(const float4*)&proj[((size_t)(b * 384 + 64 + u * 16 + row)) * 4096 + m0 + c4];
    }
#pragma unroll
    for (int r = 0; r < 8; ++r) {  // v: 2048 float4
      const int i = tid + r * 256;
      const int row = i >> 5, c4 = (i & 31) * 4;
      *(float4*)&vT[row][c4] =
          *(const float4*)&proj[((size_t)(b * 384 + 128 + u * 64 + row)) * 4096 + m0 + c4];
    }
    __syncthreads();
#pragma unroll 4
    for (int m = 0; m < 128; ++m) {
      const float kv = kT[kk][m];
      a0 = fmaf(kv, vT[dvb * 4 + 0][m], a0);
      a1 = fmaf(kv, vT[dvb * 4 + 1][m], a1);
      a2 = fmaf(kv, vT[dvb * 4 + 2][m], a2);
      a3 = fmaf(kv, vT[dvb * 4 + 3][m], a3);
    }
  }

  float* dst = &Lc[((size_t)(b * 16 + kk)) * 64 + dvb * 4];
  atomicAdd(dst + 0, a0);
  atomicAdd(dst + 1, a1);
  atomicAdd(dst + 2, a2);
  atomicAdd(dst + 3, a3);
}

// ---------------------------------------------------------------------------
// Conv worker, t-split: wave (W, H) computes t in [4H, 4H+4), acc[4] only.
// LDS: 56-row buffer (40320 B). FULL buffer zeroed ONCE before the pass loop
// (this provides the y-halo zeros: staging only writes sy in [11,75) slots;
// quads 0-1/19-21 and sy 8-10,75 edges must stay zero — round-4 bug was
// dropping this). Per pass: re-zero only rows 44..55 in pass 1 (x >= 64
// halo that held pass-0 data), stage 44 x-columns.
// ---------------------------------------------------------------------------
template <int W, int H>
__device__ __forceinline__ void conv_worker(
    _Float16* __restrict__ vL, const f16x8* __restrict__ Awl,
    const float* __restrict__ vsec, const float* __restrict__ qsec,
    const float* __restrict__ lcb, const int n, const int kap, const int tid,
    const int b, const int dv, float* __restrict__ out) {
  constexpr int TLO = 8 * H;

  f16x8 A[8];
#pragma unroll
  for (int r = 0; r < 8; ++r)
    if (rel_live<W>(r)) A[r] = Awl[r * 64];

  // one-time full zero: y-halo quads within rows + initial x-halo rows 0..11
  {
    const uint4 z = {0u, 0u, 0u, 0u};
    for (int i = tid; i < 2520; i += 256) ((uint4*)vL)[i] = z;  // 56*360 halfs
  }
  __syncthreads();

#pragma unroll 1
  for (int pass = 0; pass < 2; ++pass) {
    if (pass) {
      __syncthreads();  // protect pass-0 reads before re-stage
      // re-zero x-halo rows 44..55 (x >= 64 in pass 1; held pass-0 data)
      const uint4 z = {0u, 0u, 0u, 0u};
      uint4* zp = (uint4*)(vL + 44 * 360);
      for (int i = tid; i < 540; i += 256) zp[i] = z;
    }
    // stage 44 x-columns (f32 -> f16, u-packed quads over y); y-halo slots
    // of each row are untouched (stay zero from the one-time full zero).
    {
      const int xlo = pass ? 20 : 0;
      const int xhi = pass ? 64 : 44;
      const int roff = pass ? -20 : 12;
      for (int idx = tid; idx < 4096; idx += 256) {
        const int u = idx >> 10, g = (idx >> 4) & 63, x4 = (idx & 15) * 4;
        if (x4 >= xlo && x4 < xhi) {
          const float4 vv = *(const float4*)&vsec[(size_t)u * 262144 + g * 64 + x4];
          const int sy = g + 11;
          const int qoff = (sy >> 2) * 16 + (u << 2) + (sy & 3);
          _Float16* base = &vL[(x4 + roff) * 360 + qoff];
          base[0] = (_Float16)vv.x;
          base[360] = (_Float16)vv.y;
          base[720] = (_Float16)vv.z;
          base[1080] = (_Float16)vv.w;
        }
      }
    }
    __syncthreads();

    f32x16 acc[4];
#pragma unroll
    for (int t = 0; t < 4; ++t) acc[t] = (f32x16)0.f;

#pragma unroll 1
    for (int ss = 0; ss < 23; ++ss) {
      const int ssn = (ss == 22) ? 0 : ss + 1;  // pass-independent A stream
      const f16x8* Awn = Awl + (size_t)(ssn * 8) * 64;
      const _Float16* brow = &vL[(n + ss + 1) * 360 + 8 * kap];

      f16x8 Bq[22];
      // prologue: first 4 taus of this wave's range
#pragma unroll
      for (int i = 0; i < 4; ++i)
        if (tau_live<W, H>(TLO + i))
          Bq[TLO + i] =
              *(const f16x8*)__builtin_assume_aligned(brow + 16 * (TLO + i), 16);

#pragma unroll
      for (int tau = TLO; tau < TLO + 14; ++tau) {
        const int tpf = tau + 4;
        if (tpf < TLO + 14 && tau_live<W, H>(tpf))
          Bq[tpf] = *(const f16x8*)__builtin_assume_aligned(brow + 16 * tpf, 16);
        __builtin_amdgcn_s_setprio(1);
#pragma unroll
        for (int tt = 0; tt < 4; ++tt) {
          const int rel = tau - 2 * (4 * H + tt);
          if (rel >= 0 && rel <= 7 && rel_live<W>(rel))
            acc[tt] = __builtin_amdgcn_mfma_f32_32x32x16_f16(A[rel], Bq[tau],
                                                             acc[tt], 0, 0, 0);
        }
        __builtin_amdgcn_s_setprio(0);
        // A prefetch for next ss into dead A[rn] (same-iter last use is WAR-safe)
        const int rn = tau - (TLO + 6);
        if (rn >= 0 && rn < 8 && rel_live<W>(rn)) A[rn] = Awn[rn * 64];
      }
    }

    // epilogue: gamma = 32H + 8tt + 2W + ol
    const int c = 32 * pass + n;
#pragma unroll 1
    for (int tt = 0; tt < 4; ++tt) {
#pragma unroll
      for (int ol = 0; ol < 2; ++ol) {
        const int gamma = 32 * H + 8 * tt + 2 * W + ol;
        const float* qg = qsec + (size_t)gamma * 64 + c;
        float y0 = 0.f, y1 = 0.f, y2 = 0.f, y3 = 0.f;
#pragma unroll
        for (int e = 0; e < 8; ++e) {
          const int kk = (e & 3) + 8 * (e >> 2) + 4 * kap;
          const float cf = acc[tt][ol * 8 + e] + lcb[e];
          y0 = fmaf(qg[(size_t)(kk) * 4096], cf, y0);
          y1 = fmaf(qg[(size_t)(16 + kk) * 4096], cf, y1);
          y2 = fmaf(qg[(size_t)(32 + kk) * 4096], cf, y2);
          y3 = fmaf(qg[(size_t)(48 + kk) * 4096], cf, y3);
        }
        y0 += __shfl_xor(y0, 32);
        y1 += __shfl_xor(y1, 32);
        y2 += __shfl_xor(y2, 32);
        y3 += __shfl_xor(y3, 32);
        const float s0 = kap ? y2 : y0;  // h = 2*kap
        const float s1 = kap ? y3 : y1;  // h = 2*kap + 1
        out[((size_t)(b * 256 + (2 * kap + 0) * 64 + dv)) * 4096 + gamma * 64 + c] = s0;
        out[((size_t)(b * 256 + (2 * kap + 1) * 64 + dv)) * 4096 + gamma * 64 + c] = s1;
      }
    }
  }
}

// ---------------------------------------------------------------------------
// MFMA position-conv + Yp + Yc. Block = (dv*2+h, b); t-range split across
// h to halve accumulator state. LDS 40320 B.
// ---------------------------------------------------------------------------
__global__ __launch_bounds__(256, 3) void lambda_conv(
    const float* __restrict__ proj, const _Float16* __restrict__ Apack,
    const float* __restrict__ Lc, const float* __restrict__ b_pos,
    float* __restrict__ out) {
  const int dv = blockIdx.x >> 1;
  const int h = blockIdx.x & 1;
  const int b = blockIdx.y;
  const int tid = threadIdx.x;
  const int w = tid >> 6;          // wave: off pair base {2w, 2w+1}
  const int lane = tid & 63;
  const int n = lane & 31;         // output col within pass
  const int kap = lane >> 5;

  __shared__ __align__(16) _Float16 vL[56 * 360];  // 40320 B

  const float* vsec = proj + ((size_t)(b * 384 + 128 + dv)) * 4096;
  const float* qsec = proj + ((size_t)(b * 384)) * 4096;

  // Lc + b_pos for this lane's 8 kk channels: kk_e = (e&3) + 8*(e>>2) + 4*kap
  float lcb[8];
#pragma unroll
  for (int e = 0; e < 8; e++) {
    const int kk = (e & 3) + 8 * (e >> 2) + 4 * kap;
    lcb[e] = Lc[(b * 16 + kk) * 64 + dv] + b_pos[kk];
  }

  const f16x8* Ap = (const f16x8*)Apack;
  const f16x8* Awl = Ap + (size_t)(w * 184) * 64 + lane;  // frag (ss*8+rel)*64

  switch (w | (h << 2)) {
    case 0: conv_worker<0, 0>(vL, Awl, vsec, qsec, lcb, n, kap, tid, b, dv, out); break;
    case 1: conv_worker<1, 0>(vL, Awl, vsec, qsec, lcb, n, kap, tid, b, dv, out); break;
    case 2: conv_worker<2, 0>(vL, Awl, vsec, qsec, lcb, n, kap, tid, b, dv, out); break;
    case 3: conv_worker<3, 0>(vL, Awl, vsec, qsec, lcb, n, kap, tid, b, dv, out); break;
    case 4: conv_worker<0, 1>(vL, Awl, vsec, qsec, lcb, n, kap, tid, b, dv, out); break;
    case 5: conv_worker<1, 1>(vL, Awl, vsec, qsec, lcb, n, kap, tid, b, dv, out); break;
    case 6: conv_worker<2, 1>(vL, Awl, vsec, qsec, lcb, n, kap, tid, b, dv, out); break;
    default: conv_worker<3, 1>(vL, Awl, vsec, qsec, lcb, n, kap, tid, b, dv, out); break;
  }
}

// ---------------------------------------------------------------------------
extern "C" void kernel_launch(void* const* d_in, const int* in_sizes, int n_in,
                              void* d_out, int out_size, void* d_ws, size_t ws_size,
                              hipStream_t stream) {
  const float* x       = (const float*)d_in[0];
  const float* w_q     = (const float*)d_in[1];
  const float* w_k     = (const float*)d_in[2];
  const float* w_v     = (const float*)d_in[3];
  const float* gamma_q = (const float*)d_in[4];
  const float* beta_q  = (const float*)d_in[5];
  const float* mean_q  = (const float*)d_in[6];
  const float* var_q   = (const float*)d_in[7];
  const float* gamma_v = (const float*)d_in[8];
  const float* beta_v  = (const float*)d_in[9];
  const float* mean_v  = (const float*)d_in[10];
  const float* var_v   = (const float*)d_in[11];
  const float* w_pos   = (const float*)d_in[12];
  const float* b_pos   = (const float*)d_in[13];

  float* ws = (float*)d_ws;
  float* proj = ws;                            // 25165824 floats
  float* sb   = ws + 25165824;                 // 768 floats
  float* Lc   = sb + 768;                      // 16384 floats
  _Float16* Apack = (_Float16*)(Lc + 16384);   // 376832 halfs
  _Float16* Wp = Apack + 376832;               // 98304 halfs
  float* out = (float*)d_out;

  setup_kernel<<<1472, 256, 0, stream>>>(w_pos, w_q, w_k, w_v,
                                         gamma_q, beta_q, mean_q, var_q,
                                         gamma_v, beta_v, mean_v, var_v,
                                         sb, Lc, Wp, Apack);
  proj_gemm<<<dim3(128, 16), 256, 0, stream>>>(x, Wp, sb, proj);
  softmax_k<<<1024, 256, 0, stream>>>(proj);
  lc_kernel<<<dim3(32, 16), 256, 0, stream>>>(proj, Lc);
  lambda_conv<<<dim3(128, 16), 256, 0, stream>>>(proj, Apack, Lc, b_pos, out);
}

// Round 6
// 534.432 us; speedup vs baseline: 1.3999x; 1.0478x over previous
//
#include <hip/hip_runtime.h>
#include <stdint.h>

#define EPS 1e-3f

typedef _Float16 f16x8 __attribute__((ext_vector_type(8)));
typedef float f32x4 __attribute__((ext_vector_type(4)));
typedef float f32x16 __attribute__((ext_vector_type(16)));

// ---------------------------------------------------------------------------
// Setup: fold BN scale/bias; zero Lc; pack Wp (proj weights as f16 MFMA
// A-frags); prepack w_pos into 32x32x16-MFMA A-frags (u-packed K).
// ---------------------------------------------------------------------------
__global__ __launch_bounds__(256) void setup_kernel(
    const float* __restrict__ w_pos,
    const float* __restrict__ w_q, const float* __restrict__ w_k,
    const float* __restrict__ w_v,
    const float* __restrict__ gq, const float* __restrict__ bq,
    const float* __restrict__ mq, const float* __restrict__ vq,
    const float* __restrict__ gv, const float* __restrict__ bv,
    const float* __restrict__ mv, const float* __restrict__ vvar,
    float* __restrict__ scale_bias, float* __restrict__ Lc,
    _Float16* __restrict__ Wp, _Float16* __restrict__ Apack) {
  const int idx = blockIdx.x * 256 + threadIdx.x;
  if (idx < 384) {
    float sc, bi;
    if (idx < 64) {
      const float inv = gq[idx] * rsqrtf(vq[idx] + EPS);
      sc = inv; bi = bq[idx] - mq[idx] * inv;
    } else if (idx < 128) {
      sc = 1.f; bi = 0.f;  // k has no BN
    } else {
      const int o = idx - 128;
      const float inv = gv[o] * rsqrtf(vvar[o] + EPS);
      sc = inv; bi = bv[o] - mv[o] * inv;
    }
    scale_bias[idx] = sc;
    scale_bias[384 + idx] = bi;
  }
  if (idx < 16384) Lc[idx] = 0.f;  // lc_kernel accumulates via atomicAdd
  if (idx < 98304) {               // Wp A-frag pack: idx = ((mt*16+kt)*64+lane)*8+j
    const int j = idx & 7;
    const int lane = (idx >> 3) & 63;
    const int fr = idx >> 9;       // mt*16 + kt
    const int kt = fr & 15;
    const int mt = fr >> 4;
    const int m = mt * 32 + (lane & 31);
    const int k = kt * 16 + (lane >> 5) * 8 + j;
    float sc; const float* Wsrc;
    if (m < 64) {
      sc = gq[m] * rsqrtf(vq[m] + EPS);
      Wsrc = w_q + (size_t)m * 256;
    } else if (m < 128) {
      sc = 1.f;
      Wsrc = w_k + (size_t)(m - 64) * 256;
    } else {
      const int r = m - 128;
      sc = gv[r] * rsqrtf(vvar[r] + EPS);
      Wsrc = w_v + (size_t)r * 256;
    }
    Wp[idx] = (_Float16)(Wsrc[k] * sc);
  }
  if (idx < 376832) {  // 736 frags * 64 lanes * 8 halfs
    const int j = idx & 7;
    const int lane = (idx >> 3) & 63;
    const int f = idx >> 9;
    const int rel = f & 7;
    const int ss = (f >> 3) % 23;
    const int w = (f >> 3) / 23;
    const int m = lane & 31;
    const int kk = m & 15;
    const int ol = m >> 4;
    const int kap = lane >> 5;
    const int k = kap * 8 + j;
    const int u = k >> 2;
    const int y4 = k & 3;
    const int dy = 4 * rel + y4 - 2 * w - ol;
    float val = 0.f;
    if (dy >= 0 && dy < 23)
      val = w_pos[kk * 2116 + u * 529 + dy * 23 + ss];
    Apack[idx] = (_Float16)val;
  }
}

// ---------------------------------------------------------------------------
// Projection GEMM via f16 MFMA (round-5, fast). Block (nchunk=128, b).
// ---------------------------------------------------------------------------
__global__ __launch_bounds__(256) void proj_gemm(
    const float* __restrict__ x, const _Float16* __restrict__ Wp,
    const float* __restrict__ scale_bias, float* __restrict__ proj) {
  const int b = blockIdx.y;
  const int n0 = blockIdx.x * 32;
  const int tid = threadIdx.x;
  const int w = tid >> 6, lane = tid & 63;
  const int col = lane & 31, kap = lane >> 5;

  __shared__ __align__(16) _Float16 xT[32][264];  // 16896 B

  // stage x f32 -> f16 transposed: xT[n][k]
#pragma unroll
  for (int r = 0; r < 8; ++r) {
    const int i = tid + r * 256;  // 0..2047
    const int k = i >> 3, n4 = (i & 7) * 4;
    const float4 xv = *(const float4*)&x[((size_t)(b * 256 + k)) * 4096 + n0 + n4];
    xT[n4 + 0][k] = (_Float16)xv.x;
    xT[n4 + 1][k] = (_Float16)xv.y;
    xT[n4 + 2][k] = (_Float16)xv.z;
    xT[n4 + 3][k] = (_Float16)xv.w;
  }
  __syncthreads();

  f32x16 acc[3];
#pragma unroll
  for (int i = 0; i < 3; ++i) acc[i] = (f32x16)0.f;

  const f16x8* Wf = (const f16x8*)Wp;
#pragma unroll
  for (int kt = 0; kt < 16; ++kt) {
    const f16x8 B =
        *(const f16x8*)__builtin_assume_aligned(&xT[col][kt * 16 + kap * 8], 16);
#pragma unroll
    for (int i = 0; i < 3; ++i) {
      const f16x8 A = Wf[(size_t)(((w * 3 + i) * 16 + kt) * 64) + lane];
      acc[i] = __builtin_amdgcn_mfma_f32_32x32x16_f16(A, B, acc[i], 0, 0, 0);
    }
  }

#pragma unroll
  for (int i = 0; i < 3; ++i) {
    const int mt = w * 3 + i;
#pragma unroll
    for (int reg = 0; reg < 16; ++reg) {
      const int row = (reg & 3) + 8 * (reg >> 2) + 4 * kap;
      const int o = mt * 32 + row;
      proj[((size_t)(b * 384 + o)) * 4096 + n0 + col] =
          acc[i][reg] + scale_bias[384 + o];
    }
  }
}

// ---------------------------------------------------------------------------
// Softmax (unchanged)
// ---------------------------------------------------------------------------
__global__ __launch_bounds__(256) void softmax_k(float* __restrict__ proj) {
  const int row = blockIdx.x;
  const int b = row >> 6, c = row & 63;
  float* p = proj + ((size_t)(b * 384 + 64 + c)) * 4096;
  const int tid = threadIdx.x;

  float4 v[4];
  float vmax = -3.4e38f;
#pragma unroll
  for (int i = 0; i < 4; i++) {
    v[i] = ((const float4*)p)[tid + i * 256];
    vmax = fmaxf(vmax, fmaxf(fmaxf(v[i].x, v[i].y), fmaxf(v[i].z, v[i].w)));
  }
#pragma unroll
  for (int off = 32; off > 0; off >>= 1) vmax = fmaxf(vmax, __shfl_xor(vmax, off));
  __shared__ float redm[4], reds[4];
  if ((tid & 63) == 0) redm[tid >> 6] = vmax;
  __syncthreads();
  vmax = fmaxf(fmaxf(redm[0], redm[1]), fmaxf(redm[2], redm[3]));

  float sum = 0.f;
#pragma unroll
  for (int i = 0; i < 4; i++) {
    v[i].x = expf(v[i].x - vmax); sum += v[i].x;
    v[i].y = expf(v[i].y - vmax); sum += v[i].y;
    v[i].z = expf(v[i].z - vmax); sum += v[i].z;
    v[i].w = expf(v[i].w - vmax); sum += v[i].w;
  }
#pragma unroll
  for (int off = 32; off > 0; off >>= 1) sum += __shfl_xor(sum, off);
  if ((tid & 63) == 0) reds[tid >> 6] = sum;
  __syncthreads();
  sum = reds[0] + reds[1] + reds[2] + reds[3];
  const float inv = 1.f / sum;
#pragma unroll
  for (int i = 0; i < 4; i++) {
    v[i].x *= inv; v[i].y *= inv; v[i].z *= inv; v[i].w *= inv;
    ((float4*)p)[tid + i * 256] = v[i];
  }
}

// ---------------------------------------------------------------------------
// Lc (unchanged): LDS-tiled, atomicAdd partials.
// ---------------------------------------------------------------------------
__global__ __launch_bounds__(256) void lc_kernel(const float* __restrict__ proj,
                                                 float* __restrict__ Lc) {
  const int mc = blockIdx.x, b = blockIdx.y;
  const int m0 = mc * 128;
  const int tid = threadIdx.x;
  const int kk = tid & 15;
  const int dvb = tid >> 4;  // 16 groups of 4 dv

  __shared__ float kT[16][132];
  __shared__ float vT[64][132];

  float a0 = 0.f, a1 = 0.f, a2 = 0.f, a3 = 0.f;

  for (int u = 0; u < 4; ++u) {
    __syncthreads();
#pragma unroll
    for (int r = 0; r < 2; ++r) {  // k: 512 float4
      const int i = tid + r * 256;
      const int row = i >> 5, c4 = (i & 31) * 4;
      *(float4*)&kT[row][c4] =
          *(const float4*)&proj[((size_t)(b * 384 + 64 + u * 16 + row)) * 4096 + m0 + c4];
    }
#pragma unroll
    for (int r = 0; r < 8; ++r) {  // v: 2048 float4
      const int i = tid + r * 256;
      const int row = i >> 5, c4 = (i & 31) * 4;
      *(float4*)&vT[row][c4] =
          *(const float4*)&proj[((size_t)(b * 384 + 128 + u * 64 + row)) * 4096 + m0 + c4];
    }
    __syncthreads();
#pragma unroll 4
    for (int m = 0; m < 128; ++m) {
      const float kv = kT[kk][m];
      a0 = fmaf(kv, vT[dvb * 4 + 0][m], a0);
      a1 = fmaf(kv, vT[dvb * 4 + 1][m], a1);
      a2 = fmaf(kv, vT[dvb * 4 + 2][m], a2);
      a3 = fmaf(kv, vT[dvb * 4 + 3][m], a3);
    }
  }

  float* dst = &Lc[((size_t)(b * 16 + kk)) * 64 + dvb * 4];
  atomicAdd(dst + 0, a0);
  atomicAdd(dst + 1, a1);
  atomicAdd(dst + 2, a2);
  atomicAdd(dst + 3, a3);
}

// ---------------------------------------------------------------------------
// Conv worker (round-3 structure + per-wave ss-ROTATION to de-correlate
// waves). Wave W starts its ss-loop at SBASE = 6W (sum over ss is
// order-independent); waves then read different Bq rows / issue MFMA bursts
// out of phase -> LDS load spread, matrix pipe overlap across waves.
// A-prefetch wraparound preserves pass-boundary carry:
// after sit=22 (ss=SBASE-1), A holds frags for ss=SBASE = pass-1 start.
// Compile-time pruning: rel0 dead for W>=2, rel6 for W==0, rel7 for W!=3.
// ---------------------------------------------------------------------------
template <int W>
__device__ __forceinline__ void conv_worker(
    const _Float16* __restrict__ vL, const f16x8* __restrict__ Awl,
    const float* __restrict__ qsec, const float* __restrict__ lcb,
    const int n, const int kap, const int b, const int dv,
    float* __restrict__ out) {
  constexpr bool G0 = (W < 2);   // rel0 / tau0 live
  constexpr bool G6 = (W != 0);  // rel6 / tau20 live
  constexpr bool G7 = (W == 3);  // rel7 / tau21 live
  constexpr int SBASE = 6 * W;   // 0, 6, 12, 18 (mod 23 distinct)

  f16x8 A[8];
  if (G0) A[0] = Awl[SBASE * 8 * 64 + 0 * 64];
#pragma unroll
  for (int r = 1; r < 6; ++r) A[r] = Awl[SBASE * 8 * 64 + r * 64];
  if (G6) A[6] = Awl[SBASE * 8 * 64 + 6 * 64];
  if (G7) A[7] = Awl[SBASE * 8 * 64 + 7 * 64];

#pragma unroll 1
  for (int pass = 0; pass < 2; ++pass) {
    f32x16 acc[8];
#pragma unroll
    for (int t = 0; t < 8; t++) acc[t] = (f32x16)0.f;

#pragma unroll 1
    for (int sit = 0; sit < 23; ++sit) {
      const int ssr = sit + SBASE;
      const int ss = (ssr < 23) ? ssr : ssr - 23;        // rotated ss
      const int ssn = (ss == 22) ? 0 : ss + 1;           // next in rotated order
      const f16x8* Awn = Awl + (size_t)(ssn * 8) * 64;
      const _Float16* brow = &vL[(32 * pass + n + ss) * 360 + 8 * kap];

      f16x8 Bq[22];
      // prologue: taus 0..3
      if (G0) Bq[0] = *(const f16x8*)__builtin_assume_aligned(brow, 16);
#pragma unroll
      for (int tau = 1; tau < 4; ++tau)
        Bq[tau] = *(const f16x8*)__builtin_assume_aligned(brow + 16 * tau, 16);

#pragma unroll
      for (int tau = 0; tau < 22; ++tau) {
        // streaming prefetch, 4 taus ahead (compile-time folded guards)
        const int tpf = tau + 4;
        if (tpf < 22) {
          const bool live = (tpf == 20) ? G6 : (tpf == 21) ? G7 : true;
          if (live)
            Bq[tpf] = *(const f16x8*)__builtin_assume_aligned(brow + 16 * tpf, 16);
        }
        __builtin_amdgcn_s_setprio(1);
#pragma unroll
        for (int t = 0; t < 8; ++t) {
          const int rel = tau - 2 * t;
          if (rel < 0 || rel > 7) continue;
          if ((rel == 0 && !G0) || (rel == 6 && !G6) || (rel == 7 && !G7)) continue;
          acc[t] = __builtin_amdgcn_mfma_f32_32x32x16_f16(A[rel], Bq[tau], acc[t], 0, 0, 0);
        }
        __builtin_amdgcn_s_setprio(0);
        // A prefetch for next ss into dead A[rel] (last use at tau = 14+rel)
        if (tau >= 14) {
          const int rn = tau - 14;
          const bool live = (rn == 0) ? G0 : (rn == 6) ? G6 : (rn == 7) ? G7 : true;
          if (live) A[rn] = Awn[rn * 64];
        }
      }
    }

    // epilogue: for each (t, ol): gamma = 8t + 2W + ol
    const int c = 32 * pass + n;
#pragma unroll 1
    for (int t = 0; t < 8; ++t) {
#pragma unroll
      for (int ol = 0; ol < 2; ++ol) {
        const int gamma = 8 * t + 2 * W + ol;
        const float* qg = qsec + (size_t)gamma * 64 + c;
        float y0 = 0.f, y1 = 0.f, y2 = 0.f, y3 = 0.f;
#pragma unroll
        for (int e = 0; e < 8; ++e) {
          const int kk = (e & 3) + 8 * (e >> 2) + 4 * kap;
          const float cf = acc[t][ol * 8 + e] + lcb[e];
          y0 = fmaf(qg[(size_t)(kk) * 4096], cf, y0);
          y1 = fmaf(qg[(size_t)(16 + kk) * 4096], cf, y1);
          y2 = fmaf(qg[(size_t)(32 + kk) * 4096], cf, y2);
          y3 = fmaf(qg[(size_t)(48 + kk) * 4096], cf, y3);
        }
        y0 += __shfl_xor(y0, 32);
        y1 += __shfl_xor(y1, 32);
        y2 += __shfl_xor(y2, 32);
        y3 += __shfl_xor(y3, 32);
        const float s0 = kap ? y2 : y0;  // h = 2*kap
        const float s1 = kap ? y3 : y1;  // h = 2*kap + 1
        out[((size_t)(b * 256 + (2 * kap + 0) * 64 + dv)) * 4096 + gamma * 64 + c] = s0;
        out[((size_t)(b * 256 + (2 * kap + 1) * 64 + dv)) * 4096 + gamma * 64 + c] = s1;
      }
    }
  }
}

// ---------------------------------------------------------------------------
// MFMA position-conv + Yp + Yc. Block = (dv, b). Round-3 monolithic shell:
// full 86-row LDS staged ONCE (single barrier pair), barrier-free main loop.
// ---------------------------------------------------------------------------
__global__ __launch_bounds__(256, 2) void lambda_conv(
    const float* __restrict__ proj, const _Float16* __restrict__ Apack,
    const float* __restrict__ Lc, const float* __restrict__ b_pos,
    float* __restrict__ out) {
  const int dv = blockIdx.x;
  const int b = blockIdx.y;
  const int tid = threadIdx.x;
  const int w = tid >> 6;          // wave: off pair base {2w, 2w+1}
  const int lane = tid & 63;
  const int n = lane & 31;         // output col within pass
  const int kap = lane >> 5;

  __shared__ __align__(16) _Float16 vL[86 * 360];  // 61920 B

  // zero LDS (x- and y-halo)
  {
    const uint4 z = {0u, 0u, 0u, 0u};
    for (int i = tid; i < (86 * 360 * 2) / 16; i += 256) ((uint4*)vL)[i] = z;
  }
  __syncthreads();

  // stage v (f32 -> f16), transposed + u-packed: vL[x+11][sy>>2][u][sy&3]
  {
    const float* vsec = proj + ((size_t)(b * 384 + 128 + dv)) * 4096;
    for (int idx = tid; idx < 4096; idx += 256) {
      const int u = idx >> 10, g = (idx >> 4) & 63, c4 = (idx & 15) * 4;
      const float4 vv = *(const float4*)&vsec[(size_t)u * 262144 + g * 64 + c4];
      const int sy = g + 11;
      const int qoff = (sy >> 2) * 16 + (u << 2) + (sy & 3);
      _Float16* base = &vL[(c4 + 11) * 360 + qoff];
      base[0 * 360] = (_Float16)vv.x;
      base[1 * 360] = (_Float16)vv.y;
      base[2 * 360] = (_Float16)vv.z;
      base[3 * 360] = (_Float16)vv.w;
    }
  }
  __syncthreads();

  // Lc + b_pos for this lane's 8 kk channels: kk_e = (e&3) + 8*(e>>2) + 4*kap
  float lcb[8];
#pragma unroll
  for (int e = 0; e < 8; e++) {
    const int kk = (e & 3) + 8 * (e >> 2) + 4 * kap;
    lcb[e] = Lc[(b * 16 + kk) * 64 + dv] + b_pos[kk];
  }

  const float* qsec = proj + ((size_t)(b * 384)) * 4096;
  const f16x8* Ap = (const f16x8*)Apack;
  const f16x8* Awl = Ap + (size_t)(w * 184) * 64 + lane;  // frag (ss*8+rel)*64

  switch (w) {
    case 0: conv_worker<0>(vL, Awl, qsec, lcb, n, kap, b, dv, out); break;
    case 1: conv_worker<1>(vL, Awl, qsec, lcb, n, kap, b, dv, out); break;
    case 2: conv_worker<2>(vL, Awl, qsec, lcb, n, kap, b, dv, out); break;
    default: conv_worker<3>(vL, Awl, qsec, lcb, n, kap, b, dv, out); break;
  }
}

// ---------------------------------------------------------------------------
extern "C" void kernel_launch(void* const* d_in, const int* in_sizes, int n_in,
                              void* d_out, int out_size, void* d_ws, size_t ws_size,
                              hipStream_t stream) {
  const float* x       = (const float*)d_in[0];
  const float* w_q     = (const float*)d_in[1];
  const float* w_k     = (const float*)d_in[2];
  const float* w_v     = (const float*)d_in[3];
  const float* gamma_q = (const float*)d_in[4];
  const float* beta_q  = (const float*)d_in[5];
  const float* mean_q  = (const float*)d_in[6];
  const float* var_q   = (const float*)d_in[7];
  const float* gamma_v = (const float*)d_in[8];
  const float* beta_v  = (const float*)d_in[9];
  const float* mean_v  = (const float*)d_in[10];
  const float* var_v   = (const float*)d_in[11];
  const float* w_pos   = (const float*)d_in[12];
  const float* b_pos   = (const float*)d_in[13];

  float* ws = (float*)d_ws;
  float* proj = ws;                            // 25165824 floats
  float* sb   = ws + 25165824;                 // 768 floats
  float* Lc   = sb + 768;                      // 16384 floats
  _Float16* Apack = (_Float16*)(Lc + 16384);   // 376832 halfs
  _Float16* Wp = Apack + 376832;               // 98304 halfs
  float* out = (float*)d_out;

  setup_kernel<<<1472, 256, 0, stream>>>(w_pos, w_q, w_k, w_v,
                                         gamma_q, beta_q, mean_q, var_q,
                                         gamma_v, beta_v, mean_v, var_v,
                                         sb, Lc, Wp, Apack);
  proj_gemm<<<dim3(128, 16), 256, 0, stream>>>(x, Wp, sb, proj);
  softmax_k<<<1024, 256, 0, stream>>>(proj);
  lc_kernel<<<dim3(32, 16), 256, 0, stream>>>(proj, Lc);
  lambda_conv<<<dim3(64, 16), 256, 0, stream>>>(proj, Apack, Lc, b_pos, out);
}

// Round 7
// 526.365 us; speedup vs baseline: 1.4214x; 1.0153x over previous
//
#include <hip/hip_runtime.h>
#include <stdint.h>

#define EPS 1e-3f

typedef _Float16 f16x8 __attribute__((ext_vector_type(8)));
typedef float f32x4 __attribute__((ext_vector_type(4)));
typedef float f32x16 __attribute__((ext_vector_type(16)));

// ---------------------------------------------------------------------------
// Setup: fold BN scale/bias; zero Lc; pack Wp (proj weights as f16 MFMA
// A-frags); prepack w_pos into 32x32x16-MFMA A-frags (u-packed K).
// ---------------------------------------------------------------------------
__global__ __launch_bounds__(256) void setup_kernel(
    const float* __restrict__ w_pos,
    const float* __restrict__ w_q, const float* __restrict__ w_k,
    const float* __restrict__ w_v,
    const float* __restrict__ gq, const float* __restrict__ bq,
    const float* __restrict__ mq, const float* __restrict__ vq,
    const float* __restrict__ gv, const float* __restrict__ bv,
    const float* __restrict__ mv, const float* __restrict__ vvar,
    float* __restrict__ scale_bias, float* __restrict__ Lc,
    _Float16* __restrict__ Wp, _Float16* __restrict__ Apack) {
  const int idx = blockIdx.x * 256 + threadIdx.x;
  if (idx < 384) {
    float sc, bi;
    if (idx < 64) {
      const float inv = gq[idx] * rsqrtf(vq[idx] + EPS);
      sc = inv; bi = bq[idx] - mq[idx] * inv;
    } else if (idx < 128) {
      sc = 1.f; bi = 0.f;  // k has no BN
    } else {
      const int o = idx - 128;
      const float inv = gv[o] * rsqrtf(vvar[o] + EPS);
      sc = inv; bi = bv[o] - mv[o] * inv;
    }
    scale_bias[idx] = sc;
    scale_bias[384 + idx] = bi;
  }
  if (idx < 16384) Lc[idx] = 0.f;  // lc_kernel accumulates via atomicAdd
  if (idx < 98304) {               // Wp A-frag pack: idx = ((mt*16+kt)*64+lane)*8+j
    const int j = idx & 7;
    const int lane = (idx >> 3) & 63;
    const int fr = idx >> 9;       // mt*16 + kt
    const int kt = fr & 15;
    const int mt = fr >> 4;
    const int m = mt * 32 + (lane & 31);
    const int k = kt * 16 + (lane >> 5) * 8 + j;
    float sc; const float* Wsrc;
    if (m < 64) {
      sc = gq[m] * rsqrtf(vq[m] + EPS);
      Wsrc = w_q + (size_t)m * 256;
    } else if (m < 128) {
      sc = 1.f;
      Wsrc = w_k + (size_t)(m - 64) * 256;
    } else {
      const int r = m - 128;
      sc = gv[r] * rsqrtf(vvar[r] + EPS);
      Wsrc = w_v + (size_t)r * 256;
    }
    Wp[idx] = (_Float16)(Wsrc[k] * sc);
  }
  if (idx < 376832) {  // 736 frags * 64 lanes * 8 halfs
    const int j = idx & 7;
    const int lane = (idx >> 3) & 63;
    const int f = idx >> 9;
    const int rel = f & 7;
    const int ss = (f >> 3) % 23;
    const int w = (f >> 3) / 23;
    const int m = lane & 31;
    const int kk = m & 15;
    const int ol = m >> 4;
    const int kap = lane >> 5;
    const int k = kap * 8 + j;
    const int u = k >> 2;
    const int y4 = k & 3;
    const int dy = 4 * rel + y4 - 2 * w - ol;
    float val = 0.f;
    if (dy >= 0 && dy < 23)
      val = w_pos[kk * 2116 + u * 529 + dy * 23 + ss];
    Apack[idx] = (_Float16)val;
  }
}

// ---------------------------------------------------------------------------
// Projection GEMM via f16 MFMA (unchanged). Block (nchunk=128, b).
// ---------------------------------------------------------------------------
__global__ __launch_bounds__(256) void proj_gemm(
    const float* __restrict__ x, const _Float16* __restrict__ Wp,
    const float* __restrict__ scale_bias, float* __restrict__ proj) {
  const int b = blockIdx.y;
  const int n0 = blockIdx.x * 32;
  const int tid = threadIdx.x;
  const int w = tid >> 6, lane = tid & 63;
  const int col = lane & 31, kap = lane >> 5;

  __shared__ __align__(16) _Float16 xT[32][264];  // 16896 B

  // stage x f32 -> f16 transposed: xT[n][k]
#pragma unroll
  for (int r = 0; r < 8; ++r) {
    const int i = tid + r * 256;  // 0..2047
    const int k = i >> 3, n4 = (i & 7) * 4;
    const float4 xv = *(const float4*)&x[((size_t)(b * 256 + k)) * 4096 + n0 + n4];
    xT[n4 + 0][k] = (_Float16)xv.x;
    xT[n4 + 1][k] = (_Float16)xv.y;
    xT[n4 + 2][k] = (_Float16)xv.z;
    xT[n4 + 3][k] = (_Float16)xv.w;
  }
  __syncthreads();

  f32x16 acc[3];
#pragma unroll
  for (int i = 0; i < 3; ++i) acc[i] = (f32x16)0.f;

  const f16x8* Wf = (const f16x8*)Wp;
#pragma unroll
  for (int kt = 0; kt < 16; ++kt) {
    const f16x8 B =
        *(const f16x8*)__builtin_assume_aligned(&xT[col][kt * 16 + kap * 8], 16);
#pragma unroll
    for (int i = 0; i < 3; ++i) {
      const f16x8 A = Wf[(size_t)(((w * 3 + i) * 16 + kt) * 64) + lane];
      acc[i] = __builtin_amdgcn_mfma_f32_32x32x16_f16(A, B, acc[i], 0, 0, 0);
    }
  }

#pragma unroll
  for (int i = 0; i < 3; ++i) {
    const int mt = w * 3 + i;
#pragma unroll
    for (int reg = 0; reg < 16; ++reg) {
      const int row = (reg & 3) + 8 * (reg >> 2) + 4 * kap;
      const int o = mt * 32 + row;
      proj[((size_t)(b * 384 + o)) * 4096 + n0 + col] =
          acc[i][reg] + scale_bias[384 + o];
    }
  }
}

// ---------------------------------------------------------------------------
// k softmax STATS only (max, 1/sum per row). Softmaxed k is consumed only
// by lc — never materialize it. Saves 16 MB write + 16 MB re-read.
// ---------------------------------------------------------------------------
__global__ __launch_bounds__(256) void kstats_kernel(
    const float* __restrict__ proj, float* __restrict__ kstat) {
  const int row = blockIdx.x;          // 0..1023 = b*64 + ch
  const int b = row >> 6, c = row & 63;
  const float* p = proj + ((size_t)(b * 384 + 64 + c)) * 4096;
  const int tid = threadIdx.x;

  float4 v[4];
  float vmax = -3.4e38f;
#pragma unroll
  for (int i = 0; i < 4; i++) {
    v[i] = ((const float4*)p)[tid + i * 256];
    vmax = fmaxf(vmax, fmaxf(fmaxf(v[i].x, v[i].y), fmaxf(v[i].z, v[i].w)));
  }
#pragma unroll
  for (int off = 32; off > 0; off >>= 1) vmax = fmaxf(vmax, __shfl_xor(vmax, off));
  __shared__ float redm[4], reds[4];
  if ((tid & 63) == 0) redm[tid >> 6] = vmax;
  __syncthreads();
  vmax = fmaxf(fmaxf(redm[0], redm[1]), fmaxf(redm[2], redm[3]));

  float sum = 0.f;
#pragma unroll
  for (int i = 0; i < 4; i++) {
    sum += expf(v[i].x - vmax) + expf(v[i].y - vmax) +
           expf(v[i].z - vmax) + expf(v[i].w - vmax);
  }
#pragma unroll
  for (int off = 32; off > 0; off >>= 1) sum += __shfl_xor(sum, off);
  if ((tid & 63) == 0) reds[tid >> 6] = sum;
  __syncthreads();
  sum = reds[0] + reds[1] + reds[2] + reds[3];
  if (tid == 0) {
    kstat[(size_t)row * 2 + 0] = vmax;
    kstat[(size_t)row * 2 + 1] = 1.f / sum;
  }
}

// ---------------------------------------------------------------------------
// Lc: LDS-tiled, atomicAdd partials. Softmax applied on-the-fly at k staging
// using kstat (max, inv_sum): exp(k - max) * inv == normalized value.
// ---------------------------------------------------------------------------
__global__ __launch_bounds__(256) void lc_kernel(const float* __restrict__ proj,
                                                 const float* __restrict__ kstat,
                                                 float* __restrict__ Lc) {
  const int mc = blockIdx.x, b = blockIdx.y;
  const int m0 = mc * 128;
  const int tid = threadIdx.x;
  const int kk = tid & 15;
  const int dvb = tid >> 4;  // 16 groups of 4 dv

  __shared__ float kT[16][132];
  __shared__ float vT[64][132];

  float a0 = 0.f, a1 = 0.f, a2 = 0.f, a3 = 0.f;

  for (int u = 0; u < 4; ++u) {
    __syncthreads();
#pragma unroll
    for (int r = 0; r < 2; ++r) {  // k: 512 float4, softmax applied inline
      const int i = tid + r * 256;
      const int row = i >> 5, c4 = (i & 31) * 4;
      const int ch = u * 16 + row;
      const float kmax = kstat[((size_t)b * 64 + ch) * 2 + 0];
      const float kinv = kstat[((size_t)b * 64 + ch) * 2 + 1];
      const float4 raw =
          *(const float4*)&proj[((size_t)(b * 384 + 64 + ch)) * 4096 + m0 + c4];
      float4 sm;
      sm.x = expf(raw.x - kmax) * kinv;
      sm.y = expf(raw.y - kmax) * kinv;
      sm.z = expf(raw.z - kmax) * kinv;
      sm.w = expf(raw.w - kmax) * kinv;
      *(float4*)&kT[row][c4] = sm;
    }
#pragma unroll
    for (int r = 0; r < 8; ++r) {  // v: 2048 float4
      const int i = tid + r * 256;
      const int row = i >> 5, c4 = (i & 31) * 4;
      *(float4*)&vT[row][c4] =
          *(const float4*)&proj[((size_t)(b * 384 + 128 + u * 64 + row)) * 4096 + m0 + c4];
    }
    __syncthreads();
#pragma unroll 4
    for (int m = 0; m < 128; ++m) {
      const float kv = kT[kk][m];
      a0 = fmaf(kv, vT[dvb * 4 + 0][m], a0);
      a1 = fmaf(kv, vT[dvb * 4 + 1][m], a1);
      a2 = fmaf(kv, vT[dvb * 4 + 2][m], a2);
      a3 = fmaf(kv, vT[dvb * 4 + 3][m], a3);
    }
  }

  float* dst = &Lc[((size_t)(b * 16 + kk)) * 64 + dvb * 4];
  atomicAdd(dst + 0, a0);
  atomicAdd(dst + 1, a1);
  atomicAdd(dst + 2, a2);
  atomicAdd(dst + 3, a3);
}

// ---------------------------------------------------------------------------
// Conv worker (round-6 structure, s_setprio REMOVED — isolated A/B:
// 46 toggles/ss bracketing 2-3 MFMAs is the m190-null regime, suspected
// scheduler churn). Everything else identical: ss-rotation, compile-time
// pruning, 4-deep Bq stream, A-prefetch into dead slots.
// ---------------------------------------------------------------------------
template <int W>
__device__ __forceinline__ void conv_worker(
    const _Float16* __restrict__ vL, const f16x8* __restrict__ Awl,
    const float* __restrict__ qsec, const float* __restrict__ lcb,
    const int n, const int kap, const int b, const int dv,
    float* __restrict__ out) {
  constexpr bool G0 = (W < 2);   // rel0 / tau0 live
  constexpr bool G6 = (W != 0);  // rel6 / tau20 live
  constexpr bool G7 = (W == 3);  // rel7 / tau21 live
  constexpr int SBASE = 6 * W;   // 0, 6, 12, 18 (mod 23 distinct)

  f16x8 A[8];
  if (G0) A[0] = Awl[SBASE * 8 * 64 + 0 * 64];
#pragma unroll
  for (int r = 1; r < 6; ++r) A[r] = Awl[SBASE * 8 * 64 + r * 64];
  if (G6) A[6] = Awl[SBASE * 8 * 64 + 6 * 64];
  if (G7) A[7] = Awl[SBASE * 8 * 64 + 7 * 64];

#pragma unroll 1
  for (int pass = 0; pass < 2; ++pass) {
    f32x16 acc[8];
#pragma unroll
    for (int t = 0; t < 8; t++) acc[t] = (f32x16)0.f;

#pragma unroll 1
    for (int sit = 0; sit < 23; ++sit) {
      const int ssr = sit + SBASE;
      const int ss = (ssr < 23) ? ssr : ssr - 23;        // rotated ss
      const int ssn = (ss == 22) ? 0 : ss + 1;           // next in rotated order
      const f16x8* Awn = Awl + (size_t)(ssn * 8) * 64;
      const _Float16* brow = &vL[(32 * pass + n + ss) * 360 + 8 * kap];

      f16x8 Bq[22];
      // prologue: taus 0..3
      if (G0) Bq[0] = *(const f16x8*)__builtin_assume_aligned(brow, 16);
#pragma unroll
      for (int tau = 1; tau < 4; ++tau)
        Bq[tau] = *(const f16x8*)__builtin_assume_aligned(brow + 16 * tau, 16);

#pragma unroll
      for (int tau = 0; tau < 22; ++tau) {
        // streaming prefetch, 4 taus ahead (compile-time folded guards)
        const int tpf = tau + 4;
        if (tpf < 22) {
          const bool live = (tpf == 20) ? G6 : (tpf == 21) ? G7 : true;
          if (live)
            Bq[tpf] = *(const f16x8*)__builtin_assume_aligned(brow + 16 * tpf, 16);
        }
#pragma unroll
        for (int t = 0; t < 8; ++t) {
          const int rel = tau - 2 * t;
          if (rel < 0 || rel > 7) continue;
          if ((rel == 0 && !G0) || (rel == 6 && !G6) || (rel == 7 && !G7)) continue;
          acc[t] = __builtin_amdgcn_mfma_f32_32x32x16_f16(A[rel], Bq[tau], acc[t], 0, 0, 0);
        }
        // A prefetch for next ss into dead A[rel] (last use at tau = 14+rel)
        if (tau >= 14) {
          const int rn = tau - 14;
          const bool live = (rn == 0) ? G0 : (rn == 6) ? G6 : (rn == 7) ? G7 : true;
          if (live) A[rn] = Awn[rn * 64];
        }
      }
    }

    // epilogue: for each (t, ol): gamma = 8t + 2W + ol
    const int c = 32 * pass + n;
#pragma unroll 1
    for (int t = 0; t < 8; ++t) {
#pragma unroll
      for (int ol = 0; ol < 2; ++ol) {
        const int gamma = 8 * t + 2 * W + ol;
        const float* qg = qsec + (size_t)gamma * 64 + c;
        float y0 = 0.f, y1 = 0.f, y2 = 0.f, y3 = 0.f;
#pragma unroll
        for (int e = 0; e < 8; ++e) {
          const int kk = (e & 3) + 8 * (e >> 2) + 4 * kap;
          const float cf = acc[t][ol * 8 + e] + lcb[e];
          y0 = fmaf(qg[(size_t)(kk) * 4096], cf, y0);
          y1 = fmaf(qg[(size_t)(16 + kk) * 4096], cf, y1);
          y2 = fmaf(qg[(size_t)(32 + kk) * 4096], cf, y2);
          y3 = fmaf(qg[(size_t)(48 + kk) * 4096], cf, y3);
        }
        y0 += __shfl_xor(y0, 32);
        y1 += __shfl_xor(y1, 32);
        y2 += __shfl_xor(y2, 32);
        y3 += __shfl_xor(y3, 32);
        const float s0 = kap ? y2 : y0;  // h = 2*kap
        const float s1 = kap ? y3 : y1;  // h = 2*kap + 1
        out[((size_t)(b * 256 + (2 * kap + 0) * 64 + dv)) * 4096 + gamma * 64 + c] = s0;
        out[((size_t)(b * 256 + (2 * kap + 1) * 64 + dv)) * 4096 + gamma * 64 + c] = s1;
      }
    }
  }
}

// ---------------------------------------------------------------------------
// MFMA position-conv + Yp + Yc. Block = (dv, b). Monolithic shell:
// full 86-row LDS staged ONCE, barrier-free main loop.
// ---------------------------------------------------------------------------
__global__ __launch_bounds__(256, 2) void lambda_conv(
    const float* __restrict__ proj, const _Float16* __restrict__ Apack,
    const float* __restrict__ Lc, const float* __restrict__ b_pos,
    float* __restrict__ out) {
  const int dv = blockIdx.x;
  const int b = blockIdx.y;
  const int tid = threadIdx.x;
  const int w = tid >> 6;          // wave: off pair base {2w, 2w+1}
  const int lane = tid & 63;
  const int n = lane & 31;         // output col within pass
  const int kap = lane >> 5;

  __shared__ __align__(16) _Float16 vL[86 * 360];  // 61920 B

  // zero LDS (x- and y-halo)
  {
    const uint4 z = {0u, 0u, 0u, 0u};
    for (int i = tid; i < (86 * 360 * 2) / 16; i += 256) ((uint4*)vL)[i] = z;
  }
  __syncthreads();

  // stage v (f32 -> f16), transposed + u-packed: vL[x+11][sy>>2][u][sy&3]
  {
    const float* vsec = proj + ((size_t)(b * 384 + 128 + dv)) * 4096;
    for (int idx = tid; idx < 4096; idx += 256) {
      const int u = idx >> 10, g = (idx >> 4) & 63, c4 = (idx & 15) * 4;
      const float4 vv = *(const float4*)&vsec[(size_t)u * 262144 + g * 64 + c4];
      const int sy = g + 11;
      const int qoff = (sy >> 2) * 16 + (u << 2) + (sy & 3);
      _Float16* base = &vL[(c4 + 11) * 360 + qoff];
      base[0 * 360] = (_Float16)vv.x;
      base[1 * 360] = (_Float16)vv.y;
      base[2 * 360] = (_Float16)vv.z;
      base[3 * 360] = (_Float16)vv.w;
    }
  }
  __syncthreads();

  // Lc + b_pos for this lane's 8 kk channels: kk_e = (e&3) + 8*(e>>2) + 4*kap
  float lcb[8];
#pragma unroll
  for (int e = 0; e < 8; e++) {
    const int kk = (e & 3) + 8 * (e >> 2) + 4 * kap;
    lcb[e] = Lc[(b * 16 + kk) * 64 + dv] + b_pos[kk];
  }

  const float* qsec = proj + ((size_t)(b * 384)) * 4096;
  const f16x8* Ap = (const f16x8*)Apack;
  const f16x8* Awl = Ap + (size_t)(w * 184) * 64 + lane;  // frag (ss*8+rel)*64

  switch (w) {
    case 0: conv_worker<0>(vL, Awl, qsec, lcb, n, kap, b, dv, out); break;
    case 1: conv_worker<1>(vL, Awl, qsec, lcb, n, kap, b, dv, out); break;
    case 2: conv_worker<2>(vL, Awl, qsec, lcb, n, kap, b, dv, out); break;
    default: conv_worker<3>(vL, Awl, qsec, lcb, n, kap, b, dv, out); break;
  }
}

// ---------------------------------------------------------------------------
extern "C" void kernel_launch(void* const* d_in, const int* in_sizes, int n_in,
                              void* d_out, int out_size, void* d_ws, size_t ws_size,
                              hipStream_t stream) {
  const float* x       = (const float*)d_in[0];
  const float* w_q     = (const float*)d_in[1];
  const float* w_k     = (const float*)d_in[2];
  const float* w_v     = (const float*)d_in[3];
  const float* gamma_q = (const float*)d_in[4];
  const float* beta_q  = (const float*)d_in[5];
  const float* mean_q  = (const float*)d_in[6];
  const float* var_q   = (const float*)d_in[7];
  const float* gamma_v = (const float*)d_in[8];
  const float* beta_v  = (const float*)d_in[9];
  const float* mean_v  = (const float*)d_in[10];
  const float* var_v   = (const float*)d_in[11];
  const float* w_pos   = (const float*)d_in[12];
  const float* b_pos   = (const float*)d_in[13];

  float* ws = (float*)d_ws;
  float* proj = ws;                            // 25165824 floats
  float* sb   = ws + 25165824;                 // 768 floats
  float* Lc   = sb + 768;                      // 16384 floats
  _Float16* Apack = (_Float16*)(Lc + 16384);   // 376832 halfs
  _Float16* Wp = Apack + 376832;               // 98304 halfs
  float* kstat = (float*)(Wp + 98304);         // 2048 floats
  float* out = (float*)d_out;

  setup_kernel<<<1472, 256, 0, stream>>>(w_pos, w_q, w_k, w_v,
                                         gamma_q, beta_q, mean_q, var_q,
                                         gamma_v, beta_v, mean_v, var_v,
                                         sb, Lc, Wp, Apack);
  proj_gemm<<<dim3(128, 16), 256, 0, stream>>>(x, Wp, sb, proj);
  kstats_kernel<<<1024, 256, 0, stream>>>(proj, kstat);
  lc_kernel<<<dim3(32, 16), 256, 0, stream>>>(proj, kstat, Lc);
  lambda_conv<<<dim3(64, 16), 256, 0, stream>>>(proj, Apack, Lc, b_pos, out);
}

// Round 8
// 519.760 us; speedup vs baseline: 1.4394x; 1.0127x over previous
//
#include <hip/hip_runtime.h>
#include <stdint.h>

#define EPS 1e-3f

typedef _Float16 f16x8 __attribute__((ext_vector_type(8)));
typedef float f32x4 __attribute__((ext_vector_type(4)));
typedef float f32x16 __attribute__((ext_vector_type(16)));

// ---------------------------------------------------------------------------
// Setup: fold BN scale/bias; zero Lc; pack Wp (proj weights as f16 MFMA
// A-frags); prepack w_pos into 32x32x16-MFMA A-frags (u-packed K).
// ---------------------------------------------------------------------------
__global__ __launch_bounds__(256) void setup_kernel(
    const float* __restrict__ w_pos,
    const float* __restrict__ w_q, const float* __restrict__ w_k,
    const float* __restrict__ w_v,
    const float* __restrict__ gq, const float* __restrict__ bq,
    const float* __restrict__ mq, const float* __restrict__ vq,
    const float* __restrict__ gv, const float* __restrict__ bv,
    const float* __restrict__ mv, const float* __restrict__ vvar,
    float* __restrict__ scale_bias, float* __restrict__ Lc,
    _Float16* __restrict__ Wp, _Float16* __restrict__ Apack) {
  const int idx = blockIdx.x * 256 + threadIdx.x;
  if (idx < 384) {
    float sc, bi;
    if (idx < 64) {
      const float inv = gq[idx] * rsqrtf(vq[idx] + EPS);
      sc = inv; bi = bq[idx] - mq[idx] * inv;
    } else if (idx < 128) {
      sc = 1.f; bi = 0.f;  // k has no BN
    } else {
      const int o = idx - 128;
      const float inv = gv[o] * rsqrtf(vvar[o] + EPS);
      sc = inv; bi = bv[o] - mv[o] * inv;
    }
    scale_bias[idx] = sc;
    scale_bias[384 + idx] = bi;
  }
  if (idx < 16384) Lc[idx] = 0.f;  // lc_kernel accumulates via atomicAdd
  if (idx < 98304) {               // Wp A-frag pack: idx = ((mt*16+kt)*64+lane)*8+j
    const int j = idx & 7;
    const int lane = (idx >> 3) & 63;
    const int fr = idx >> 9;       // mt*16 + kt
    const int kt = fr & 15;
    const int mt = fr >> 4;
    const int m = mt * 32 + (lane & 31);
    const int k = kt * 16 + (lane >> 5) * 8 + j;
    float sc; const float* Wsrc;
    if (m < 64) {
      sc = gq[m] * rsqrtf(vq[m] + EPS);
      Wsrc = w_q + (size_t)m * 256;
    } else if (m < 128) {
      sc = 1.f;
      Wsrc = w_k + (size_t)(m - 64) * 256;
    } else {
      const int r = m - 128;
      sc = gv[r] * rsqrtf(vvar[r] + EPS);
      Wsrc = w_v + (size_t)r * 256;
    }
    Wp[idx] = (_Float16)(Wsrc[k] * sc);
  }
  if (idx < 376832) {  // 736 frags * 64 lanes * 8 halfs
    const int j = idx & 7;
    const int lane = (idx >> 3) & 63;
    const int f = idx >> 9;
    const int rel = f & 7;
    const int ss = (f >> 3) % 23;
    const int w = (f >> 3) / 23;
    const int m = lane & 31;
    const int kk = m & 15;
    const int ol = m >> 4;
    const int kap = lane >> 5;
    const int k = kap * 8 + j;
    const int u = k >> 2;
    const int y4 = k & 3;
    const int dy = 4 * rel + y4 - 2 * w - ol;
    float val = 0.f;
    if (dy >= 0 && dy < 23)
      val = w_pos[kk * 2116 + u * 529 + dy * 23 + ss];
    Apack[idx] = (_Float16)val;
  }
}

// ---------------------------------------------------------------------------
// Projection GEMM via f16 MFMA (unchanged). Block (nchunk=128, b).
// ---------------------------------------------------------------------------
__global__ __launch_bounds__(256) void proj_gemm(
    const float* __restrict__ x, const _Float16* __restrict__ Wp,
    const float* __restrict__ scale_bias, float* __restrict__ proj) {
  const int b = blockIdx.y;
  const int n0 = blockIdx.x * 32;
  const int tid = threadIdx.x;
  const int w = tid >> 6, lane = tid & 63;
  const int col = lane & 31, kap = lane >> 5;

  __shared__ __align__(16) _Float16 xT[32][264];  // 16896 B

  // stage x f32 -> f16 transposed: xT[n][k]
#pragma unroll
  for (int r = 0; r < 8; ++r) {
    const int i = tid + r * 256;  // 0..2047
    const int k = i >> 3, n4 = (i & 7) * 4;
    const float4 xv = *(const float4*)&x[((size_t)(b * 256 + k)) * 4096 + n0 + n4];
    xT[n4 + 0][k] = (_Float16)xv.x;
    xT[n4 + 1][k] = (_Float16)xv.y;
    xT[n4 + 2][k] = (_Float16)xv.z;
    xT[n4 + 3][k] = (_Float16)xv.w;
  }
  __syncthreads();

  f32x16 acc[3];
#pragma unroll
  for (int i = 0; i < 3; ++i) acc[i] = (f32x16)0.f;

  const f16x8* Wf = (const f16x8*)Wp;
#pragma unroll
  for (int kt = 0; kt < 16; ++kt) {
    const f16x8 B =
        *(const f16x8*)__builtin_assume_aligned(&xT[col][kt * 16 + kap * 8], 16);
#pragma unroll
    for (int i = 0; i < 3; ++i) {
      const f16x8 A = Wf[(size_t)(((w * 3 + i) * 16 + kt) * 64) + lane];
      acc[i] = __builtin_amdgcn_mfma_f32_32x32x16_f16(A, B, acc[i], 0, 0, 0);
    }
  }

#pragma unroll
  for (int i = 0; i < 3; ++i) {
    const int mt = w * 3 + i;
#pragma unroll
    for (int reg = 0; reg < 16; ++reg) {
      const int row = (reg & 3) + 8 * (reg >> 2) + 4 * kap;
      const int o = mt * 32 + row;
      proj[((size_t)(b * 384 + o)) * 4096 + n0 + col] =
          acc[i][reg] + scale_bias[384 + o];
    }
  }
}

// ---------------------------------------------------------------------------
// k softmax STATS only (max, 1/sum per row).
// ---------------------------------------------------------------------------
__global__ __launch_bounds__(256) void kstats_kernel(
    const float* __restrict__ proj, float* __restrict__ kstat) {
  const int row = blockIdx.x;          // 0..1023 = b*64 + ch
  const int b = row >> 6, c = row & 63;
  const float* p = proj + ((size_t)(b * 384 + 64 + c)) * 4096;
  const int tid = threadIdx.x;

  float4 v[4];
  float vmax = -3.4e38f;
#pragma unroll
  for (int i = 0; i < 4; i++) {
    v[i] = ((const float4*)p)[tid + i * 256];
    vmax = fmaxf(vmax, fmaxf(fmaxf(v[i].x, v[i].y), fmaxf(v[i].z, v[i].w)));
  }
#pragma unroll
  for (int off = 32; off > 0; off >>= 1) vmax = fmaxf(vmax, __shfl_xor(vmax, off));
  __shared__ float redm[4], reds[4];
  if ((tid & 63) == 0) redm[tid >> 6] = vmax;
  __syncthreads();
  vmax = fmaxf(fmaxf(redm[0], redm[1]), fmaxf(redm[2], redm[3]));

  float sum = 0.f;
#pragma unroll
  for (int i = 0; i < 4; i++) {
    sum += expf(v[i].x - vmax) + expf(v[i].y - vmax) +
           expf(v[i].z - vmax) + expf(v[i].w - vmax);
  }
#pragma unroll
  for (int off = 32; off > 0; off >>= 1) sum += __shfl_xor(sum, off);
  if ((tid & 63) == 0) reds[tid >> 6] = sum;
  __syncthreads();
  sum = reds[0] + reds[1] + reds[2] + reds[3];
  if (tid == 0) {
    kstat[(size_t)row * 2 + 0] = vmax;
    kstat[(size_t)row * 2 + 1] = 1.f / sum;
  }
}

// ---------------------------------------------------------------------------
// Lc: LDS-tiled, atomicAdd partials. Softmax applied on-the-fly at k staging.
// ---------------------------------------------------------------------------
__global__ __launch_bounds__(256) void lc_kernel(const float* __restrict__ proj,
                                                 const float* __restrict__ kstat,
                                                 float* __restrict__ Lc) {
  const int mc = blockIdx.x, b = blockIdx.y;
  const int m0 = mc * 128;
  const int tid = threadIdx.x;
  const int kk = tid & 15;
  const int dvb = tid >> 4;  // 16 groups of 4 dv

  __shared__ float kT[16][132];
  __shared__ float vT[64][132];

  float a0 = 0.f, a1 = 0.f, a2 = 0.f, a3 = 0.f;

  for (int u = 0; u < 4; ++u) {
    __syncthreads();
#pragma unroll
    for (int r = 0; r < 2; ++r) {  // k: 512 float4, softmax applied inline
      const int i = tid + r * 256;
      const int row = i >> 5, c4 = (i & 31) * 4;
      const int ch = u * 16 + row;
      const float kmax = kstat[((size_t)b * 64 + ch) * 2 + 0];
      const float kinv = kstat[((size_t)b * 64 + ch) * 2 + 1];
      const float4 raw =
          *(const float4*)&proj[((size_t)(b * 384 + 64 + ch)) * 4096 + m0 + c4];
      float4 sm;
      sm.x = expf(raw.x - kmax) * kinv;
      sm.y = expf(raw.y - kmax) * kinv;
      sm.z = expf(raw.z - kmax) * kinv;
      sm.w = expf(raw.w - kmax) * kinv;
      *(float4*)&kT[row][c4] = sm;
    }
#pragma unroll
    for (int r = 0; r < 8; ++r) {  // v: 2048 float4
      const int i = tid + r * 256;
      const int row = i >> 5, c4 = (i & 31) * 4;
      *(float4*)&vT[row][c4] =
          *(const float4*)&proj[((size_t)(b * 384 + 128 + u * 64 + row)) * 4096 + m0 + c4];
    }
    __syncthreads();
#pragma unroll 4
    for (int m = 0; m < 128; ++m) {
      const float kv = kT[kk][m];
      a0 = fmaf(kv, vT[dvb * 4 + 0][m], a0);
      a1 = fmaf(kv, vT[dvb * 4 + 1][m], a1);
      a2 = fmaf(kv, vT[dvb * 4 + 2][m], a2);
      a3 = fmaf(kv, vT[dvb * 4 + 3][m], a3);
    }
  }

  float* dst = &Lc[((size_t)(b * 16 + kk)) * 64 + dvb * 4];
  atomicAdd(dst + 0, a0);
  atomicAdd(dst + 1, a1);
  atomicAdd(dst + 2, a2);
  atomicAdd(dst + 3, a3);
}

// ---------------------------------------------------------------------------
// Conv worker: EXACT round-3 configuration (best measured: 330 µs).
// Branchless compile-time pruning, s_setprio around MFMA cluster (A/B round 7
// proved +20 µs), NO ss-rotation (A/B rounds 3 vs 6 proved rotation -10 µs),
// 4-deep Bq stream, A-prefetch into dead slots.
// ---------------------------------------------------------------------------
template <int W>
__device__ __forceinline__ void conv_worker(
    const _Float16* __restrict__ vL, const f16x8* __restrict__ Awl,
    const float* __restrict__ qsec, const float* __restrict__ lcb,
    const int n, const int kap, const int b, const int dv,
    float* __restrict__ out) {
  constexpr bool G0 = (W < 2);   // rel0 / tau0 live
  constexpr bool G6 = (W != 0);  // rel6 / tau20 live
  constexpr bool G7 = (W == 3);  // rel7 / tau21 live

  f16x8 A[8];
  if (G0) A[0] = Awl[0 * 64];
#pragma unroll
  for (int r = 1; r < 6; ++r) A[r] = Awl[r * 64];
  if (G6) A[6] = Awl[6 * 64];
  if (G7) A[7] = Awl[7 * 64];

#pragma unroll 1
  for (int pass = 0; pass < 2; ++pass) {
    f32x16 acc[8];
#pragma unroll
    for (int t = 0; t < 8; t++) acc[t] = (f32x16)0.f;

#pragma unroll 1
    for (int ss = 0; ss < 23; ++ss) {
      const int ssn = (ss == 22) ? 0 : ss + 1;  // pass-independent A stream
      const f16x8* Awn = Awl + (size_t)(ssn * 8) * 64;
      const _Float16* brow = &vL[(32 * pass + n + ss) * 360 + 8 * kap];

      f16x8 Bq[22];
      // prologue: taus 0..3
      if (G0) Bq[0] = *(const f16x8*)__builtin_assume_aligned(brow, 16);
#pragma unroll
      for (int tau = 1; tau < 4; ++tau)
        Bq[tau] = *(const f16x8*)__builtin_assume_aligned(brow + 16 * tau, 16);

#pragma unroll
      for (int tau = 0; tau < 22; ++tau) {
        // streaming prefetch, 4 taus ahead (compile-time folded guards)
        const int tpf = tau + 4;
        if (tpf < 22) {
          const bool live = (tpf == 20) ? G6 : (tpf == 21) ? G7 : true;
          if (live)
            Bq[tpf] = *(const f16x8*)__builtin_assume_aligned(brow + 16 * tpf, 16);
        }
        __builtin_amdgcn_s_setprio(1);
#pragma unroll
        for (int t = 0; t < 8; ++t) {
          const int rel = tau - 2 * t;
          if (rel < 0 || rel > 7) continue;
          if ((rel == 0 && !G0) || (rel == 6 && !G6) || (rel == 7 && !G7)) continue;
          acc[t] = __builtin_amdgcn_mfma_f32_32x32x16_f16(A[rel], Bq[tau], acc[t], 0, 0, 0);
        }
        __builtin_amdgcn_s_setprio(0);
        // A prefetch for next ss into dead A[rel] (last use at tau = 14+rel)
        if (tau >= 14) {
          const int rn = tau - 14;
          const bool live = (rn == 0) ? G0 : (rn == 6) ? G6 : (rn == 7) ? G7 : true;
          if (live) A[rn] = Awn[rn * 64];
        }
      }
    }

    // epilogue: for each (t, ol): gamma = 8t + 2W + ol
    const int c = 32 * pass + n;
#pragma unroll 1
    for (int t = 0; t < 8; ++t) {
#pragma unroll
      for (int ol = 0; ol < 2; ++ol) {
        const int gamma = 8 * t + 2 * W + ol;
        const float* qg = qsec + (size_t)gamma * 64 + c;
        float y0 = 0.f, y1 = 0.f, y2 = 0.f, y3 = 0.f;
#pragma unroll
        for (int e = 0; e < 8; ++e) {
          const int kk = (e & 3) + 8 * (e >> 2) + 4 * kap;
          const float cf = acc[t][ol * 8 + e] + lcb[e];
          y0 = fmaf(qg[(size_t)(kk) * 4096], cf, y0);
          y1 = fmaf(qg[(size_t)(16 + kk) * 4096], cf, y1);
          y2 = fmaf(qg[(size_t)(32 + kk) * 4096], cf, y2);
          y3 = fmaf(qg[(size_t)(48 + kk) * 4096], cf, y3);
        }
        y0 += __shfl_xor(y0, 32);
        y1 += __shfl_xor(y1, 32);
        y2 += __shfl_xor(y2, 32);
        y3 += __shfl_xor(y3, 32);
        const float s0 = kap ? y2 : y0;  // h = 2*kap
        const float s1 = kap ? y3 : y1;  // h = 2*kap + 1
        out[((size_t)(b * 256 + (2 * kap + 0) * 64 + dv)) * 4096 + gamma * 64 + c] = s0;
        out[((size_t)(b * 256 + (2 * kap + 1) * 64 + dv)) * 4096 + gamma * 64 + c] = s1;
      }
    }
  }
}

// ---------------------------------------------------------------------------
// MFMA position-conv + Yp + Yc. Grid = 1024 linear; XCD-aware mapping:
// wgid -> (xcd = wgid&7, slot = wgid>>3); b = xcd*2 + slot/64, dv = slot%64.
// All 64 dv-blocks of a batch land on ONE XCD -> q-section (1 MB/b) is
// fetched once per XCD instead of 8x; epilogue q-loads become L2 hits.
// Work is perfectly balanced: 128 blocks per XCD either way.
// ---------------------------------------------------------------------------
__global__ __launch_bounds__(256, 2) void lambda_conv(
    const float* __restrict__ proj, const _Float16* __restrict__ Apack,
    const float* __restrict__ Lc, const float* __restrict__ b_pos,
    float* __restrict__ out) {
  const int wgid = blockIdx.x;
  const int xcd = wgid & 7;
  const int slot = wgid >> 3;
  const int b = (xcd << 1) | (slot >> 6);
  const int dv = slot & 63;
  const int tid = threadIdx.x;
  const int w = tid >> 6;          // wave: off pair base {2w, 2w+1}
  const int lane = tid & 63;
  const int n = lane & 31;         // output col within pass
  const int kap = lane >> 5;

  __shared__ __align__(16) _Float16 vL[86 * 360];  // 61920 B

  // zero LDS (x- and y-halo)
  {
    const uint4 z = {0u, 0u, 0u, 0u};
    for (int i = tid; i < (86 * 360 * 2) / 16; i += 256) ((uint4*)vL)[i] = z;
  }
  __syncthreads();

  // stage v (f32 -> f16), transposed + u-packed: vL[x+11][sy>>2][u][sy&3]
  {
    const float* vsec = proj + ((size_t)(b * 384 + 128 + dv)) * 4096;
    for (int idx = tid; idx < 4096; idx += 256) {
      const int u = idx >> 10, g = (idx >> 4) & 63, c4 = (idx & 15) * 4;
      const float4 vv = *(const float4*)&vsec[(size_t)u * 262144 + g * 64 + c4];
      const int sy = g + 11;
      const int qoff = (sy >> 2) * 16 + (u << 2) + (sy & 3);
      _Float16* base = &vL[(c4 + 11) * 360 + qoff];
      base[0 * 360] = (_Float16)vv.x;
      base[1 * 360] = (_Float16)vv.y;
      base[2 * 360] = (_Float16)vv.z;
      base[3 * 360] = (_Float16)vv.w;
    }
  }
  __syncthreads();

  // Lc + b_pos for this lane's 8 kk channels: kk_e = (e&3) + 8*(e>>2) + 4*kap
  float lcb[8];
#pragma unroll
  for (int e = 0; e < 8; e++) {
    const int kk = (e & 3) + 8 * (e >> 2) + 4 * kap;
    lcb[e] = Lc[(b * 16 + kk) * 64 + dv] + b_pos[kk];
  }

  const float* qsec = proj + ((size_t)(b * 384)) * 4096;
  const f16x8* Ap = (const f16x8*)Apack;
  const f16x8* Awl = Ap + (size_t)(w * 184) * 64 + lane;  // frag (ss*8+rel)*64

  switch (w) {
    case 0: conv_worker<0>(vL, Awl, qsec, lcb, n, kap, b, dv, out); break;
    case 1: conv_worker<1>(vL, Awl, qsec, lcb, n, kap, b, dv, out); break;
    case 2: conv_worker<2>(vL, Awl, qsec, lcb, n, kap, b, dv, out); break;
    default: conv_worker<3>(vL, Awl, qsec, lcb, n, kap, b, dv, out); break;
  }
}

// ---------------------------------------------------------------------------
extern "C" void kernel_launch(void* const* d_in, const int* in_sizes, int n_in,
                              void* d_out, int out_size, void* d_ws, size_t ws_size,
                              hipStream_t stream) {
  const float* x       = (const float*)d_in[0];
  const float* w_q     = (const float*)d_in[1];
  const float* w_k     = (const float*)d_in[2];
  const float* w_v     = (const float*)d_in[3];
  const float* gamma_q = (const float*)d_in[4];
  const float* beta_q  = (const float*)d_in[5];
  const float* mean_q  = (const float*)d_in[6];
  const float* var_q   = (const float*)d_in[7];
  const float* gamma_v = (const float*)d_in[8];
  const float* beta_v  = (const float*)d_in[9];
  const float* mean_v  = (const float*)d_in[10];
  const float* var_v   = (const float*)d_in[11];
  const float* w_pos   = (const float*)d_in[12];
  const float* b_pos   = (const float*)d_in[13];

  float* ws = (float*)d_ws;
  float* proj = ws;                            // 25165824 floats
  float* sb   = ws + 25165824;                 // 768 floats
  float* Lc   = sb + 768;                      // 16384 floats
  _Float16* Apack = (_Float16*)(Lc + 16384);   // 376832 halfs
  _Float16* Wp = Apack + 376832;               // 98304 halfs
  float* kstat = (float*)(Wp + 98304);         // 2048 floats
  float* out = (float*)d_out;

  setup_kernel<<<1472, 256, 0, stream>>>(w_pos, w_q, w_k, w_v,
                                         gamma_q, beta_q, mean_q, var_q,
                                         gamma_v, beta_v, mean_v, var_v,
                                         sb, Lc, Wp, Apack);
  proj_gemm<<<dim3(128, 16), 256, 0, stream>>>(x, Wp, sb, proj);
  kstats_kernel<<<1024, 256, 0, stream>>>(proj, kstat);
  lc_kernel<<<dim3(32, 16), 256, 0, stream>>>(proj, kstat, Lc);
  lambda_conv<<<1024, 256, 0, stream>>>(proj, Apack, Lc, b_pos, out);
}

// Round 9
// 506.611 us; speedup vs baseline: 1.4768x; 1.0260x over previous
//
#include <hip/hip_runtime.h>
#include <stdint.h>

#define EPS 1e-3f

typedef _Float16 f16x8 __attribute__((ext_vector_type(8)));
typedef float f32x4 __attribute__((ext_vector_type(4)));
typedef float f32x16 __attribute__((ext_vector_type(16)));

// ---------------------------------------------------------------------------
// Setup: fold BN scale/bias; zero Lc; pack Wp (proj weights as f16 MFMA
// A-frags); prepack w_pos into 32x32x16-MFMA A-frags (u-packed K).
// ---------------------------------------------------------------------------
__global__ __launch_bounds__(256) void setup_kernel(
    const float* __restrict__ w_pos,
    const float* __restrict__ w_q, const float* __restrict__ w_k,
    const float* __restrict__ w_v,
    const float* __restrict__ gq, const float* __restrict__ bq,
    const float* __restrict__ mq, const float* __restrict__ vq,
    const float* __restrict__ gv, const float* __restrict__ bv,
    const float* __restrict__ mv, const float* __restrict__ vvar,
    float* __restrict__ scale_bias, float* __restrict__ Lc,
    _Float16* __restrict__ Wp, _Float16* __restrict__ Apack) {
  const int idx = blockIdx.x * 256 + threadIdx.x;
  if (idx < 384) {
    float sc, bi;
    if (idx < 64) {
      const float inv = gq[idx] * rsqrtf(vq[idx] + EPS);
      sc = inv; bi = bq[idx] - mq[idx] * inv;
    } else if (idx < 128) {
      sc = 1.f; bi = 0.f;  // k has no BN
    } else {
      const int o = idx - 128;
      const float inv = gv[o] * rsqrtf(vvar[o] + EPS);
      sc = inv; bi = bv[o] - mv[o] * inv;
    }
    scale_bias[idx] = sc;
    scale_bias[384 + idx] = bi;
  }
  if (idx < 16384) Lc[idx] = 0.f;  // lc_kernel accumulates via atomicAdd
  if (idx < 98304) {               // Wp A-frag pack: idx = ((mt*16+kt)*64+lane)*8+j
    const int j = idx & 7;
    const int lane = (idx >> 3) & 63;
    const int fr = idx >> 9;       // mt*16 + kt
    const int kt = fr & 15;
    const int mt = fr >> 4;
    const int m = mt * 32 + (lane & 31);
    const int k = kt * 16 + (lane >> 5) * 8 + j;
    float sc; const float* Wsrc;
    if (m < 64) {
      sc = gq[m] * rsqrtf(vq[m] + EPS);
      Wsrc = w_q + (size_t)m * 256;
    } else if (m < 128) {
      sc = 1.f;
      Wsrc = w_k + (size_t)(m - 64) * 256;
    } else {
      const int r = m - 128;
      sc = gv[r] * rsqrtf(vvar[r] + EPS);
      Wsrc = w_v + (size_t)r * 256;
    }
    Wp[idx] = (_Float16)(Wsrc[k] * sc);
  }
  if (idx < 376832) {  // 736 frags * 64 lanes * 8 halfs
    const int j = idx & 7;
    const int lane = (idx >> 3) & 63;
    const int f = idx >> 9;
    const int rel = f & 7;
    const int ss = (f >> 3) % 23;
    const int w = (f >> 3) / 23;
    const int m = lane & 31;
    const int kk = m & 15;
    const int ol = m >> 4;
    const int kap = lane >> 5;
    const int k = kap * 8 + j;
    const int u = k >> 2;
    const int y4 = k & 3;
    const int dy = 4 * rel + y4 - 2 * w - ol;
    float val = 0.f;
    if (dy >= 0 && dy < 23)
      val = w_pos[kk * 2116 + u * 529 + dy * 23 + ss];
    Apack[idx] = (_Float16)val;
  }
}

// ---------------------------------------------------------------------------
// Projection GEMM via f16 MFMA. Block (nchunk=128, b).
// Output split: q rows (o<64) -> projq f32 (epilogue consumes f32);
// k+v rows -> projkv f16 (all consumers convert to/accept f16 anyway).
// Halves proj write traffic and all downstream k/v reads.
// ---------------------------------------------------------------------------
__global__ __launch_bounds__(256) void proj_gemm(
    const float* __restrict__ x, const _Float16* __restrict__ Wp,
    const float* __restrict__ scale_bias, float* __restrict__ projq,
    _Float16* __restrict__ projkv) {
  const int b = blockIdx.y;
  const int n0 = blockIdx.x * 32;
  const int tid = threadIdx.x;
  const int w = tid >> 6, lane = tid & 63;
  const int col = lane & 31, kap = lane >> 5;

  __shared__ __align__(16) _Float16 xT[32][264];  // 16896 B

  // stage x f32 -> f16 transposed: xT[n][k]
#pragma unroll
  for (int r = 0; r < 8; ++r) {
    const int i = tid + r * 256;  // 0..2047
    const int k = i >> 3, n4 = (i & 7) * 4;
    const float4 xv = *(const float4*)&x[((size_t)(b * 256 + k)) * 4096 + n0 + n4];
    xT[n4 + 0][k] = (_Float16)xv.x;
    xT[n4 + 1][k] = (_Float16)xv.y;
    xT[n4 + 2][k] = (_Float16)xv.z;
    xT[n4 + 3][k] = (_Float16)xv.w;
  }
  __syncthreads();

  f32x16 acc[3];
#pragma unroll
  for (int i = 0; i < 3; ++i) acc[i] = (f32x16)0.f;

  const f16x8* Wf = (const f16x8*)Wp;
#pragma unroll
  for (int kt = 0; kt < 16; ++kt) {
    const f16x8 B =
        *(const f16x8*)__builtin_assume_aligned(&xT[col][kt * 16 + kap * 8], 16);
#pragma unroll
    for (int i = 0; i < 3; ++i) {
      const f16x8 A = Wf[(size_t)(((w * 3 + i) * 16 + kt) * 64) + lane];
      acc[i] = __builtin_amdgcn_mfma_f32_32x32x16_f16(A, B, acc[i], 0, 0, 0);
    }
  }

#pragma unroll
  for (int i = 0; i < 3; ++i) {
    const int mt = w * 3 + i;
#pragma unroll
    for (int reg = 0; reg < 16; ++reg) {
      const int row = (reg & 3) + 8 * (reg >> 2) + 4 * kap;
      const int o = mt * 32 + row;
      const float val = acc[i][reg] + scale_bias[384 + o];
      if (mt < 2)
        projq[((size_t)(b * 64 + o)) * 4096 + n0 + col] = val;
      else
        projkv[((size_t)(b * 320 + (o - 64))) * 4096 + n0 + col] = (_Float16)val;
    }
  }
}

// ---------------------------------------------------------------------------
// k softmax STATS only (max, 1/sum per row) from f16 k.
// ---------------------------------------------------------------------------
__global__ __launch_bounds__(256) void kstats_kernel(
    const _Float16* __restrict__ projkv, float* __restrict__ kstat) {
  const int row = blockIdx.x;          // 0..1023 = b*64 + ch
  const int b = row >> 6, c = row & 63;
  const f16x8* p8 = (const f16x8*)(projkv + ((size_t)(b * 320 + c)) * 4096);
  const int tid = threadIdx.x;

  f16x8 h[2];
  h[0] = p8[tid];
  h[1] = p8[tid + 256];
  float vmax = -3.4e38f;
#pragma unroll
  for (int i = 0; i < 2; ++i)
#pragma unroll
    for (int e = 0; e < 8; ++e) vmax = fmaxf(vmax, (float)h[i][e]);
#pragma unroll
  for (int off = 32; off > 0; off >>= 1) vmax = fmaxf(vmax, __shfl_xor(vmax, off));
  __shared__ float redm[4], reds[4];
  if ((tid & 63) == 0) redm[tid >> 6] = vmax;
  __syncthreads();
  vmax = fmaxf(fmaxf(redm[0], redm[1]), fmaxf(redm[2], redm[3]));

  float sum = 0.f;
#pragma unroll
  for (int i = 0; i < 2; ++i)
#pragma unroll
    for (int e = 0; e < 8; ++e) sum += expf((float)h[i][e] - vmax);
#pragma unroll
  for (int off = 32; off > 0; off >>= 1) sum += __shfl_xor(sum, off);
  if ((tid & 63) == 0) reds[tid >> 6] = sum;
  __syncthreads();
  sum = reds[0] + reds[1] + reds[2] + reds[3];
  if (tid == 0) {
    kstat[(size_t)row * 2 + 0] = vmax;
    kstat[(size_t)row * 2 + 1] = 1.f / sum;
  }
}

// ---------------------------------------------------------------------------
// Lc: LDS-tiled, atomicAdd partials. f16 k/v inputs; softmax applied at
// k staging using kstat.
// ---------------------------------------------------------------------------
__global__ __launch_bounds__(256) void lc_kernel(
    const _Float16* __restrict__ projkv, const float* __restrict__ kstat,
    float* __restrict__ Lc) {
  const int mc = blockIdx.x, b = blockIdx.y;
  const int m0 = mc * 128;
  const int tid = threadIdx.x;
  const int kk = tid & 15;
  const int dvb = tid >> 4;  // 16 groups of 4 dv

  __shared__ float kT[16][132];
  __shared__ float vT[64][132];

  float a0 = 0.f, a1 = 0.f, a2 = 0.f, a3 = 0.f;

  for (int u = 0; u < 4; ++u) {
    __syncthreads();
    {  // k: one f16x8 per thread (16 rows x 128 cols), softmax inline
      const int row = tid >> 4, c8 = (tid & 15) * 8;
      const int ch = u * 16 + row;
      const float kmax = kstat[((size_t)b * 64 + ch) * 2 + 0];
      const float kinv = kstat[((size_t)b * 64 + ch) * 2 + 1];
      const f16x8 raw =
          *(const f16x8*)&projkv[((size_t)(b * 320 + ch)) * 4096 + m0 + c8];
#pragma unroll
      for (int e = 0; e < 8; ++e)
        kT[row][c8 + e] = expf((float)raw[e] - kmax) * kinv;
    }
#pragma unroll
    for (int r = 0; r < 4; ++r) {  // v: 64 rows x 128 cols f16
      const int i = tid + r * 256;
      const int row = i >> 4, c8 = (i & 15) * 8;
      const f16x8 raw =
          *(const f16x8*)&projkv[((size_t)(b * 320 + 64 + u * 64 + row)) * 4096 + m0 + c8];
#pragma unroll
      for (int e = 0; e < 8; ++e) vT[row][c8 + e] = (float)raw[e];
    }
    __syncthreads();
#pragma unroll 4
    for (int m = 0; m < 128; ++m) {
      const float kv = kT[kk][m];
      a0 = fmaf(kv, vT[dvb * 4 + 0][m], a0);
      a1 = fmaf(kv, vT[dvb * 4 + 1][m], a1);
      a2 = fmaf(kv, vT[dvb * 4 + 2][m], a2);
      a3 = fmaf(kv, vT[dvb * 4 + 3][m], a3);
    }
  }

  float* dst = &Lc[((size_t)(b * 16 + kk)) * 64 + dvb * 4];
  atomicAdd(dst + 0, a0);
  atomicAdd(dst + 1, a1);
  atomicAdd(dst + 2, a2);
  atomicAdd(dst + 3, a3);
}

// ---------------------------------------------------------------------------
// Conv worker: EXACT round-3 configuration (best measured: 330 µs).
// Branchless compile-time pruning, s_setprio around MFMA cluster (A/B r7:
// removal cost 20 µs), NO ss-rotation (A/B r3 vs r6: -10 µs), NO XCD swizzle
// (A/B r3 vs r8: -14 µs), 4-deep Bq stream, A-prefetch into dead slots.
// ---------------------------------------------------------------------------
template <int W>
__device__ __forceinline__ void conv_worker(
    const _Float16* __restrict__ vL, const f16x8* __restrict__ Awl,
    const float* __restrict__ qsec, const float* __restrict__ lcb,
    const int n, const int kap, const int b, const int dv,
    float* __restrict__ out) {
  constexpr bool G0 = (W < 2);   // rel0 / tau0 live
  constexpr bool G6 = (W != 0);  // rel6 / tau20 live
  constexpr bool G7 = (W == 3);  // rel7 / tau21 live

  f16x8 A[8];
  if (G0) A[0] = Awl[0 * 64];
#pragma unroll
  for (int r = 1; r < 6; ++r) A[r] = Awl[r * 64];
  if (G6) A[6] = Awl[6 * 64];
  if (G7) A[7] = Awl[7 * 64];

#pragma unroll 1
  for (int pass = 0; pass < 2; ++pass) {
    f32x16 acc[8];
#pragma unroll
    for (int t = 0; t < 8; t++) acc[t] = (f32x16)0.f;

#pragma unroll 1
    for (int ss = 0; ss < 23; ++ss) {
      const int ssn = (ss == 22) ? 0 : ss + 1;  // pass-independent A stream
      const f16x8* Awn = Awl + (size_t)(ssn * 8) * 64;
      const _Float16* brow = &vL[(32 * pass + n + ss) * 360 + 8 * kap];

      f16x8 Bq[22];
      // prologue: taus 0..3
      if (G0) Bq[0] = *(const f16x8*)__builtin_assume_aligned(brow, 16);
#pragma unroll
      for (int tau = 1; tau < 4; ++tau)
        Bq[tau] = *(const f16x8*)__builtin_assume_aligned(brow + 16 * tau, 16);

#pragma unroll
      for (int tau = 0; tau < 22; ++tau) {
        // streaming prefetch, 4 taus ahead (compile-time folded guards)
        const int tpf = tau + 4;
        if (tpf < 22) {
          const bool live = (tpf == 20) ? G6 : (tpf == 21) ? G7 : true;
          if (live)
            Bq[tpf] = *(const f16x8*)__builtin_assume_aligned(brow + 16 * tpf, 16);
        }
        __builtin_amdgcn_s_setprio(1);
#pragma unroll
        for (int t = 0; t < 8; ++t) {
          const int rel = tau - 2 * t;
          if (rel < 0 || rel > 7) continue;
          if ((rel == 0 && !G0) || (rel == 6 && !G6) || (rel == 7 && !G7)) continue;
          acc[t] = __builtin_amdgcn_mfma_f32_32x32x16_f16(A[rel], Bq[tau], acc[t], 0, 0, 0);
        }
        __builtin_amdgcn_s_setprio(0);
        // A prefetch for next ss into dead A[rel] (last use at tau = 14+rel)
        if (tau >= 14) {
          const int rn = tau - 14;
          const bool live = (rn == 0) ? G0 : (rn == 6) ? G6 : (rn == 7) ? G7 : true;
          if (live) A[rn] = Awn[rn * 64];
        }
      }
    }

    // epilogue: for each (t, ol): gamma = 8t + 2W + ol
    const int c = 32 * pass + n;
#pragma unroll 1
    for (int t = 0; t < 8; ++t) {
#pragma unroll
      for (int ol = 0; ol < 2; ++ol) {
        const int gamma = 8 * t + 2 * W + ol;
        const float* qg = qsec + (size_t)gamma * 64 + c;
        float y0 = 0.f, y1 = 0.f, y2 = 0.f, y3 = 0.f;
#pragma unroll
        for (int e = 0; e < 8; ++e) {
          const int kk = (e & 3) + 8 * (e >> 2) + 4 * kap;
          const float cf = acc[t][ol * 8 + e] + lcb[e];
          y0 = fmaf(qg[(size_t)(kk) * 4096], cf, y0);
          y1 = fmaf(qg[(size_t)(16 + kk) * 4096], cf, y1);
          y2 = fmaf(qg[(size_t)(32 + kk) * 4096], cf, y2);
          y3 = fmaf(qg[(size_t)(48 + kk) * 4096], cf, y3);
        }
        y0 += __shfl_xor(y0, 32);
        y1 += __shfl_xor(y1, 32);
        y2 += __shfl_xor(y2, 32);
        y3 += __shfl_xor(y3, 32);
        const float s0 = kap ? y2 : y0;  // h = 2*kap
        const float s1 = kap ? y3 : y1;  // h = 2*kap + 1
        out[((size_t)(b * 256 + (2 * kap + 0) * 64 + dv)) * 4096 + gamma * 64 + c] = s0;
        out[((size_t)(b * 256 + (2 * kap + 1) * 64 + dv)) * 4096 + gamma * 64 + c] = s1;
      }
    }
  }
}

// ---------------------------------------------------------------------------
// MFMA position-conv + Yp + Yc. Block = (dv, b) plain mapping (r3 config).
// v staged from f16 projkv (pure repack, no convert).
// ---------------------------------------------------------------------------
__global__ __launch_bounds__(256, 2) void lambda_conv(
    const float* __restrict__ projq, const _Float16* __restrict__ projkv,
    const _Float16* __restrict__ Apack,
    const float* __restrict__ Lc, const float* __restrict__ b_pos,
    float* __restrict__ out) {
  const int dv = blockIdx.x;
  const int b = blockIdx.y;
  const int tid = threadIdx.x;
  const int w = tid >> 6;          // wave: off pair base {2w, 2w+1}
  const int lane = tid & 63;
  const int n = lane & 31;         // output col within pass
  const int kap = lane >> 5;

  __shared__ __align__(16) _Float16 vL[86 * 360];  // 61920 B

  // zero LDS (x- and y-halo)
  {
    const uint4 z = {0u, 0u, 0u, 0u};
    for (int i = tid; i < (86 * 360 * 2) / 16; i += 256) ((uint4*)vL)[i] = z;
  }
  __syncthreads();

  // stage v (f16 -> f16 repack), transposed + u-packed: vL[x+11][sy>>2][u][sy&3]
  {
    const _Float16* vsec = projkv + ((size_t)(b * 320 + 64 + dv)) * 4096;
    for (int idx = tid; idx < 2048; idx += 256) {
      const int u = idx >> 9, g = (idx >> 3) & 63, c8 = (idx & 7) * 8;
      const f16x8 vv = *(const f16x8*)&vsec[(size_t)u * 262144 + g * 64 + c8];
      const int sy = g + 11;
      const int qoff = (sy >> 2) * 16 + (u << 2) + (sy & 3);
      _Float16* base = &vL[(c8 + 11) * 360 + qoff];
#pragma unroll
      for (int e = 0; e < 8; ++e) base[(size_t)e * 360] = vv[e];
    }
  }
  __syncthreads();

  // Lc + b_pos for this lane's 8 kk channels: kk_e = (e&3) + 8*(e>>2) + 4*kap
  float lcb[8];
#pragma unroll
  for (int e = 0; e < 8; e++) {
    const int kk = (e & 3) + 8 * (e >> 2) + 4 * kap;
    lcb[e] = Lc[(b * 16 + kk) * 64 + dv] + b_pos[kk];
  }

  const float* qsec = projq + ((size_t)(b * 64)) * 4096;
  const f16x8* Ap = (const f16x8*)Apack;
  const f16x8* Awl = Ap + (size_t)(w * 184) * 64 + lane;  // frag (ss*8+rel)*64

  switch (w) {
    case 0: conv_worker<0>(vL, Awl, qsec, lcb, n, kap, b, dv, out); break;
    case 1: conv_worker<1>(vL, Awl, qsec, lcb, n, kap, b, dv, out); break;
    case 2: conv_worker<2>(vL, Awl, qsec, lcb, n, kap, b, dv, out); break;
    default: conv_worker<3>(vL, Awl, qsec, lcb, n, kap, b, dv, out); break;
  }
}

// ---------------------------------------------------------------------------
extern "C" void kernel_launch(void* const* d_in, const int* in_sizes, int n_in,
                              void* d_out, int out_size, void* d_ws, size_t ws_size,
                              hipStream_t stream) {
  const float* x       = (const float*)d_in[0];
  const float* w_q     = (const float*)d_in[1];
  const float* w_k     = (const float*)d_in[2];
  const float* w_v     = (const float*)d_in[3];
  const float* gamma_q = (const float*)d_in[4];
  const float* beta_q  = (const float*)d_in[5];
  const float* mean_q  = (const float*)d_in[6];
  const float* var_q   = (const float*)d_in[7];
  const float* gamma_v = (const float*)d_in[8];
  const float* beta_v  = (const float*)d_in[9];
  const float* mean_v  = (const float*)d_in[10];
  const float* var_v   = (const float*)d_in[11];
  const float* w_pos   = (const float*)d_in[12];
  const float* b_pos   = (const float*)d_in[13];

  float* ws = (float*)d_ws;
  float* projq = ws;                                   // 16*64*4096 = 4194304 floats
  _Float16* projkv = (_Float16*)(ws + 4194304);        // 16*320*4096 = 20971520 halfs
  float* sb = ws + 4194304 + 10485760;                 // 768 floats
  float* Lc = sb + 768;                                // 16384 floats
  _Float16* Apack = (_Float16*)(Lc + 16384);           // 376832 halfs
  _Float16* Wp = Apack + 376832;                       // 98304 halfs
  float* kstat = (float*)(Wp + 98304);                 // 2048 floats
  float* out = (float*)d_out;

  setup_kernel<<<1472, 256, 0, stream>>>(w_pos, w_q, w_k, w_v,
                                         gamma_q, beta_q, mean_q, var_q,
                                         gamma_v, beta_v, mean_v, var_v,
                                         sb, Lc, Wp, Apack);
  proj_gemm<<<dim3(128, 16), 256, 0, stream>>>(x, Wp, sb, projq, projkv);
  kstats_kernel<<<1024, 256, 0, stream>>>(projkv, kstat);
  lc_kernel<<<dim3(32, 16), 256, 0, stream>>>(projkv, kstat, Lc);
  lambda_conv<<<dim3(64, 16), 256, 0, stream>>>(projq, projkv, Apack, Lc, b_pos, out);
}